// Round 7
// baseline (218.989 us; speedup 1.0000x reference)
//
#include <hip/hip_runtime.h>
#include <stdint.h>

// PointNet Feature Propagation, MI355X.
//  K0 : W f32 -> w1b bf16 [256][64], w2b bf16 [256][256]
//  K1 : exact f32 3-NN + inverse-distance weights -> idxw [B][N][8] (4 n/thread)
//  K2 : ztb = W2 @ p2, bf16, o-blocked [b][og16][s1024][16o]
//  K2b: y1 = W1 @ p1, bf16, o-blocked [b][og16][n4096][16o]
//  K3a: y2 = y1 + sum_k w_k * ztb[idx_k]  (LDS-staged gather) -> bf16 + BN partials
//  K3b: partials -> per-channel scale/bias
//  K3c: y2 -> LDS transpose -> BN+ReLU -> d_out f32 [b][o][n]

#define B_   16
#define N_   4096
#define S_   1024
#define D1_  64
#define D2_  256
#define OC_  256

typedef __attribute__((ext_vector_type(8))) short bf16x8;
typedef __attribute__((ext_vector_type(4))) float f32x4;
typedef __attribute__((ext_vector_type(4))) unsigned int u32x4;
typedef __attribute__((ext_vector_type(2))) unsigned int u32x2;

// workspace layout (bytes)  (ws is 256 MiB per harness fills)
#define IDXW_OFF 0u           // 2 MB
#define ZTB_OFF  2097152u     // 8 MB
#define Y1_OFF   10485760u    // 32 MB
#define Y2_OFF   44040192u    // 32 MB
#define PART_OFF 77594624u    // 64 KB
#define SB_OFF   77660160u    // 2 KB
#define W1B_OFF  77662208u    // 32 KB
#define W2B_OFF  77694976u    // 128 KB
#define WS_NEED  77826048u

__device__ __forceinline__ uint16_t f2bf(float f) {
    union { float f; uint32_t u; } v; v.f = f;
    uint32_t r = v.u + 0x7FFFu + ((v.u >> 16) & 1u);   // RNE
    return (uint16_t)(r >> 16);
}
__device__ __forceinline__ float bf2f(uint32_t h) {
    union { uint32_t u; float f; } v; v.u = h << 16;
    return v.f;
}

// ---------------- K0 ----------------
__global__ void k0_prep(const float* __restrict__ W,
                        uint16_t* __restrict__ w1b, uint16_t* __restrict__ w2b) {
    int e = blockIdx.x * 256 + threadIdx.x;
    if (e >= OC_ * 320) return;
    int o = e / 320, c = e % 320;
    uint16_t b = f2bf(W[e]);
    if (c < 64) w1b[o * 64 + c] = b;
    else        w2b[o * 256 + (c - 64)] = b;
}

// ---------------- K1: three_nn, 4 n per thread ----------------
#define INSERT(d, sidx, d0, d1, d2, i0, i1, i2) do {                      \
    bool ca = (d) < (d2); bool cb = (d) < (d1); bool cc = (d) < (d0);     \
    float _n1 = __builtin_amdgcn_fmed3f((d), (d0), (d1));                 \
    float _n2 = __builtin_amdgcn_fmed3f((d), (d1), (d2));                 \
    int _j2 = cb ? (i1) : (ca ? (sidx) : (i2));                           \
    int _j1 = cc ? (i0) : (cb ? (sidx) : (i1));                           \
    i0 = cc ? (sidx) : (i0);                                              \
    d0 = fminf((d), (d0)); d1 = _n1; d2 = _n2; i1 = _j1; i2 = _j2;        \
} while (0)

__global__ void k1_threenn(const float* __restrict__ xyz1,
                           const float* __restrict__ xyz2,
                           int* __restrict__ idxw) {
    __shared__ float4 pts[4 * 257];
    int b  = blockIdx.y;
    int n0 = blockIdx.x * 256;
    int t  = threadIdx.x;

    for (int s = t; s < S_; s += 256) {
        const float* p = xyz2 + ((size_t)b * S_ + s) * 3;
        pts[(s >> 8) * 257 + (s & 255)] = make_float4(p[0], p[1], p[2], 0.f);
    }
    __syncthreads();

    int chunk = t & 3, nidx = t >> 2;     // 64 n-slots x 4 n each
    float qx[4], qy[4], qz[4];
    #pragma unroll
    for (int k = 0; k < 4; k++) {
        const float* q = xyz1 + ((size_t)b * N_ + n0 + nidx + k * 64) * 3;
        qx[k] = q[0]; qy[k] = q[1]; qz[k] = q[2];
    }
    float d0[4], d1[4], d2[4]; int i0[4], i1[4], i2[4];
    #pragma unroll
    for (int k = 0; k < 4; k++) { d0[k] = d1[k] = d2[k] = 3.4e38f; i0[k] = i1[k] = i2[k] = 0; }

    const float4* base = pts + chunk * 257;
    int sbase = chunk * 256;
    #pragma unroll 2
    for (int j = 0; j < 256; j++) {
        float4 q = base[j];
        int s = sbase + j;
        #pragma unroll
        for (int k = 0; k < 4; k++) {
            float dx = qx[k] - q.x, dy = qy[k] - q.y, dz = qz[k] - q.z;
            float d = fmaf(dz, dz, fmaf(dy, dy, dx * dx));
            INSERT(d, s, d0[k], d1[k], d2[k], i0[k], i1[k], i2[k]);
        }
    }
    #pragma unroll
    for (int m = 1; m <= 2; m <<= 1) {
        #pragma unroll
        for (int k = 0; k < 4; k++) {
            float e0 = __shfl_xor(d0[k], m), e1 = __shfl_xor(d1[k], m), e2 = __shfl_xor(d2[k], m);
            int   g0 = __shfl_xor(i0[k], m), g1 = __shfl_xor(i1[k], m), g2 = __shfl_xor(i2[k], m);
            INSERT(e0, g0, d0[k], d1[k], d2[k], i0[k], i1[k], i2[k]);
            INSERT(e1, g1, d0[k], d1[k], d2[k], i0[k], i1[k], i2[k]);
            INSERT(e2, g2, d0[k], d1[k], d2[k], i0[k], i1[k], i2[k]);
        }
    }
    if (chunk == 0) {
        float* fw = (float*)idxw;
        #pragma unroll
        for (int k = 0; k < 4; k++) {
            float r0 = 1.0f / (d0[k] + 1e-8f), r1 = 1.0f / (d1[k] + 1e-8f), r2 = 1.0f / (d2[k] + 1e-8f);
            float rs = r0 + r1 + r2;
            int bb = (b * N_ + n0 + nidx + k * 64) * 8;
            idxw[bb + 0] = i0[k]; idxw[bb + 1] = i1[k]; idxw[bb + 2] = i2[k];
            fw[bb + 4] = r0 / rs; fw[bb + 5] = r1 / rs; fw[bb + 6] = r2 / rs;
        }
    }
}

// ---------------- K2: ztb = W2@p2, o-blocked bf16 ----------------
__global__ void k2_z(const float* __restrict__ p2, const uint16_t* __restrict__ w2b,
                     uint16_t* __restrict__ ztb) {
    __shared__ char smem[40960];
    uint16_t* a_t = (uint16_t*)smem;            // [64 s][64 c], 128B rows, swz <<4
    uint16_t* w_t = (uint16_t*)(smem + 8192);   // [256 o][64 c]
    int b = blockIdx.y, s0 = blockIdx.x * 64;
    int t = threadIdx.x, l = t & 63, w = t >> 6;   // 4 waves

    f32x4 acc[4][4] = {};   // [mi(s)][oj(o)]
    for (int ck = 0; ck < 4; ck++) {
        __syncthreads();
        {
            int sA = w * 16 + (l & 15);
            const float* p2b = p2 + ((size_t)b * D2_ + (size_t)ck * 64) * S_ + s0;
            #pragma unroll
            for (int j = 0; j < 8; j++) {
                int cp = (l >> 4) + 4 * j;
                float lo = p2b[(size_t)(2 * cp) * S_ + sA];
                float hi = p2b[(size_t)(2 * cp + 1) * S_ + sA];
                uint32_t pk = (uint32_t)f2bf(lo) | ((uint32_t)f2bf(hi) << 16);
                *(uint32_t*)((char*)a_t + sA * 128 + ((cp * 4) ^ ((sA & 7) << 4))) = pk;
            }
        }
        {
            int wp = t & 31, orow0 = t >> 5;
            #pragma unroll 4
            for (int jj = 0; jj < 32; jj++) {
                int o = orow0 + 8 * jj;
                uint32_t v = *(const uint32_t*)(w2b + (size_t)o * 256 + ck * 64 + 2 * wp);
                *(uint32_t*)((char*)w_t + o * 128 + ((wp * 4) ^ ((o & 7) << 4))) = v;
            }
        }
        __syncthreads();
        #pragma unroll
        for (int ks = 0; ks < 2; ks++) {
            bf16x8 a[4], bb[4];
            int co = ks * 32 + (l >> 4) * 8;
            #pragma unroll
            for (int mi = 0; mi < 4; mi++) {
                int s = mi * 16 + (l & 15);
                a[mi] = *(const bf16x8*)((const char*)a_t + s * 128 + ((co * 2) ^ ((s & 7) << 4)));
            }
            #pragma unroll
            for (int oj = 0; oj < 4; oj++) {
                int o = w * 64 + oj * 16 + (l & 15);
                bb[oj] = *(const bf16x8*)((const char*)w_t + o * 128 + ((co * 2) ^ ((o & 7) << 4)));
            }
            #pragma unroll
            for (int mi = 0; mi < 4; mi++)
                #pragma unroll
                for (int oj = 0; oj < 4; oj++)
                    acc[mi][oj] = __builtin_amdgcn_mfma_f32_16x16x32_bf16(
                        a[mi], bb[oj], acc[mi][oj], 0, 0, 0);
        }
    }
    __syncthreads();
    char* tz = smem;   // [64 s][512 B], swz <<5
    #pragma unroll
    for (int mi = 0; mi < 4; mi++)
        #pragma unroll
        for (int oj = 0; oj < 4; oj++)
            #pragma unroll
            for (int r = 0; r < 4; r++) {
                int sl = mi * 16 + (l >> 4) * 4 + r;
                int o  = w * 64 + oj * 16 + (l & 15);
                *(uint16_t*)(tz + sl * 512 + ((o * 2) ^ ((sl & 7) << 5))) = f2bf(acc[mi][oj][r]);
            }
    __syncthreads();
    {
        int og = t >> 4, rr = t & 15;
        uint16_t* zb = ztb + ((size_t)(b * 16 + og) * S_ + s0) * 16;
        #pragma unroll
        for (int k = 0; k < 4; k++) {
            int s = rr * 4 + k;
            u32x4 v0 = *(u32x4*)(tz + s * 512 + ((og * 32) ^ ((s & 7) << 5)));
            u32x4 v1 = *(u32x4*)(tz + s * 512 + (((og * 32) ^ ((s & 7) << 5)) | 16));
            __builtin_nontemporal_store(v0, (u32x4*)(zb + (size_t)s * 16));
            __builtin_nontemporal_store(v1, (u32x4*)(zb + (size_t)s * 16 + 8));
        }
    }
}

// ---------------- K2b: y1 = W1@p1, o-blocked bf16 ----------------
__global__ void __launch_bounds__(256, 4)
k2b(const float* __restrict__ p1, const uint16_t* __restrict__ w1b,
    uint16_t* __restrict__ y1) {
    int i = blockIdx.x;            // 2048
    int b = i >> 7, n0 = (i & 127) * 32;
    int t = threadIdx.x, l = t & 63, w = t >> 6;
    int oW = w * 64;
    __shared__ uint16_t pt[32 * 64];   // [n][c], 128B rows, swz <<4
    {
        int nn = t & 31;
        const float* p1b = p1 + (size_t)b * D1_ * N_ + n0;
        #pragma unroll
        for (int j = 0; j < 4; j++) {
            int cp = (t >> 5) + 8 * j;
            float lo = p1b[(size_t)(2 * cp) * N_ + nn];
            float hi = p1b[(size_t)(2 * cp + 1) * N_ + nn];
            uint32_t pk = (uint32_t)f2bf(lo) | ((uint32_t)f2bf(hi) << 16);
            *(uint32_t*)((char*)pt + nn * 128 + ((cp * 4) ^ ((nn & 7) << 4))) = pk;
        }
    }
    bf16x8 af[2][4];
    #pragma unroll
    for (int ks = 0; ks < 2; ks++)
        #pragma unroll
        for (int mi = 0; mi < 4; mi++) {
            int o = oW + mi * 16 + (l & 15);
            af[ks][mi] = *(const bf16x8*)(w1b + (size_t)o * 64 + ks * 32 + (l >> 4) * 8);
        }
    f32x4 acc[4][2] = {};   // [mi(o)][bj(n)]
    __syncthreads();
    #pragma unroll
    for (int ks = 0; ks < 2; ks++) {
        bf16x8 bf[2];
        int co = ks * 32 + (l >> 4) * 8;
        #pragma unroll
        for (int bj = 0; bj < 2; bj++) {
            int nn = bj * 16 + (l & 15);
            bf[bj] = *(const bf16x8*)((const char*)pt + nn * 128 + ((co * 2) ^ ((nn & 7) << 4)));
        }
        #pragma unroll
        for (int mi = 0; mi < 4; mi++)
            #pragma unroll
            for (int bj = 0; bj < 2; bj++)
                acc[mi][bj] = __builtin_amdgcn_mfma_f32_16x16x32_bf16(
                    af[ks][mi], bf[bj], acc[mi][bj], 0, 0, 0);
    }
    #pragma unroll
    for (int mi = 0; mi < 4; mi++) {
        int og = w * 4 + mi;
        uint16_t* yb = y1 + ((size_t)(b * 16 + og)) * N_ * 16;
        #pragma unroll
        for (int bj = 0; bj < 2; bj++) {
            int n = n0 + bj * 16 + (l & 15);
            int oo = (l >> 4) * 4;
            u32x2 v;
            v.x = (uint32_t)f2bf(acc[mi][bj][0]) | ((uint32_t)f2bf(acc[mi][bj][1]) << 16);
            v.y = (uint32_t)f2bf(acc[mi][bj][2]) | ((uint32_t)f2bf(acc[mi][bj][3]) << 16);
            __builtin_nontemporal_store(v, (u32x2*)(yb + (size_t)n * 16 + oo));
        }
    }
}

// ---------------- K3a: LDS-staged gather -> y2 bf16 + BN partials ----------------
__global__ void __launch_bounds__(512, 4)
k3a(const uint16_t* __restrict__ y1, const uint16_t* __restrict__ ztb,
    const int* __restrict__ idxw, uint16_t* __restrict__ y2,
    float* __restrict__ partials) {
    __shared__ char zsm[49152];          // [1024 s][48B] rows (32B used)
    __shared__ float red[8][16][2];
    int bi = blockIdx.x;                 // 512: b*32 + og*2 + nh
    int b = bi >> 5, og = (bi >> 1) & 15, nh = bi & 1;
    int u = threadIdx.x, l = u & 63, w = u >> 6;
    {
        const u32x4* src = (const u32x4*)(ztb + ((size_t)(b * 16 + og)) * S_ * 16);
        #pragma unroll
        for (int k = 0; k < 4; k++) {
            int g = k * 512 + u;
            u32x4 v = src[g];
            *(u32x4*)(zsm + (g >> 1) * 48 + (g & 1) * 16) = v;
        }
    }
    __syncthreads();
    int q = l >> 2, sub = l & 3;
    float s1l[4] = {0.f, 0.f, 0.f, 0.f}, s2l[4] = {0.f, 0.f, 0.f, 0.f};
    int nbase = nh * 2048 + w * 256;
    const uint16_t* y1b = y1 + ((size_t)(b * 16 + og)) * N_ * 16;
    uint16_t* y2b = y2 + ((size_t)(b * 16 + og)) * N_ * 16;
    for (int it = 0; it < 16; it++) {
        int n = nbase + it * 16 + q;
        u32x2 y1v = __builtin_nontemporal_load((const u32x2*)(y1b + (size_t)n * 16 + sub * 4));
        const int* ib = idxw + ((size_t)(b * N_ + n)) * 8;
        int4   iv = *(const int4*)ib;
        float4 wv = *((const float4*)ib + 1);
        u32x2 z0 = *(const u32x2*)(zsm + iv.x * 48 + sub * 8);
        u32x2 z1 = *(const u32x2*)(zsm + iv.y * 48 + sub * 8);
        u32x2 z2 = *(const u32x2*)(zsm + iv.z * 48 + sub * 8);
        float a0 = bf2f(y1v.x & 0xffff) + wv.x * bf2f(z0.x & 0xffff) + wv.y * bf2f(z1.x & 0xffff) + wv.z * bf2f(z2.x & 0xffff);
        float a1 = bf2f(y1v.x >> 16)    + wv.x * bf2f(z0.x >> 16)    + wv.y * bf2f(z1.x >> 16)    + wv.z * bf2f(z2.x >> 16);
        float a2 = bf2f(y1v.y & 0xffff) + wv.x * bf2f(z0.y & 0xffff) + wv.y * bf2f(z1.y & 0xffff) + wv.z * bf2f(z2.y & 0xffff);
        float a3 = bf2f(y1v.y >> 16)    + wv.x * bf2f(z0.y >> 16)    + wv.y * bf2f(z1.y >> 16)    + wv.z * bf2f(z2.y >> 16);
        s1l[0] += a0; s2l[0] += a0 * a0;
        s1l[1] += a1; s2l[1] += a1 * a1;
        s1l[2] += a2; s2l[2] += a2 * a2;
        s1l[3] += a3; s2l[3] += a3 * a3;
        u32x2 vv;
        vv.x = (uint32_t)f2bf(a0) | ((uint32_t)f2bf(a1) << 16);
        vv.y = (uint32_t)f2bf(a2) | ((uint32_t)f2bf(a3) << 16);
        __builtin_nontemporal_store(vv, (u32x2*)(y2b + (size_t)n * 16 + sub * 4));
    }
    #pragma unroll
    for (int m = 4; m <= 32; m <<= 1)
        #pragma unroll
        for (int j = 0; j < 4; j++) {
            s1l[j] += __shfl_xor(s1l[j], m);
            s2l[j] += __shfl_xor(s2l[j], m);
        }
    if (l < 4) {
        #pragma unroll
        for (int j = 0; j < 4; j++) {
            red[w][sub * 4 + j][0] = s1l[j];
            red[w][sub * 4 + j][1] = s2l[j];
        }
    }
    __syncthreads();
    if (u < 32) {
        int oi = u >> 1, st = u & 1;
        float s = 0.f;
        #pragma unroll
        for (int ww = 0; ww < 8; ww++) s += red[ww][oi][st];
        partials[(size_t)bi * 32 + oi * 2 + st] = s;
    }
}

// ---------------- K3b ----------------
__global__ void k3b(const float* __restrict__ partials, const float* __restrict__ gamma,
                    const float* __restrict__ beta, float* __restrict__ sb) {
    int o = threadIdx.x;           // 256
    int og = o >> 4, oo = o & 15;
    float a = 0.f, q = 0.f;
    for (int t = 0; t < 32; t++) {
        int bb = t >> 1, nh = t & 1;
        int bi = bb * 32 + og * 2 + nh;
        a += partials[(size_t)bi * 32 + oo * 2];
        q += partials[(size_t)bi * 32 + oo * 2 + 1];
    }
    float mean = a / 65536.0f;
    float var  = q / 65536.0f - mean * mean;
    float scale = gamma[o] * rsqrtf(var + 1e-5f);
    sb[o * 2] = scale;
    sb[o * 2 + 1] = beta[o] - mean * scale;
}

// ---------------- K3c: y2 -> LDS transpose -> BN+ReLU -> out ----------------
__global__ void __launch_bounds__(256, 8)
k3c(const uint16_t* __restrict__ y2, const float* __restrict__ sb,
    float* __restrict__ out) {
    __shared__ uint16_t ty[16 * 256];   // [16 o][256 n], byte XOR bit4 by (o&7)
    int bi = blockIdx.x;                // 4096: b*256 + og*16 + nc
    int b = bi >> 8, og = (bi >> 4) & 15, nc = bi & 15;
    int u = threadIdx.x;
    const uint16_t* src = y2 + (((size_t)(b * 16 + og)) * N_ + nc * 256) * 16;
    u32x4 va = __builtin_nontemporal_load((const u32x4*)(src + (size_t)u * 16));
    u32x4 vb = __builtin_nontemporal_load((const u32x4*)(src + (size_t)u * 16 + 8));
    uint32_t words[8] = {va.x, va.y, va.z, va.w, vb.x, vb.y, vb.z, vb.w};
    #pragma unroll
    for (int h = 0; h < 8; h++) {
        int o0 = h * 2, o1 = h * 2 + 1;
        *(uint16_t*)((char*)ty + o0 * 512 + ((u * 2) ^ ((o0 & 7) << 4))) = (uint16_t)(words[h] & 0xffff);
        *(uint16_t*)((char*)ty + o1 * 512 + ((u * 2) ^ ((o1 & 7) << 4))) = (uint16_t)(words[h] >> 16);
    }
    __syncthreads();
    int o = u >> 4, nb = (u & 15) * 16;
    int x = (o & 7) << 4;
    int basea = o * 512 + nb * 2;
    u32x4 lo = *(const u32x4*)((const char*)ty + (basea ^ x));
    u32x4 hi = *(const u32x4*)((const char*)ty + ((basea + 16) ^ x));
    int o_g = og * 16 + o;
    float scale = sb[o_g * 2], bias = sb[o_g * 2 + 1];
    float* dst = out + ((size_t)(b * OC_ + o_g)) * N_ + nc * 256 + nb;
    uint32_t wsv[8] = {lo.x, lo.y, lo.z, lo.w, hi.x, hi.y, hi.z, hi.w};
    #pragma unroll
    for (int g2 = 0; g2 < 4; g2++) {
        f32x4 r;
        r.x = fmaxf(0.f, fmaf(bf2f(wsv[g2 * 2] & 0xffff),     scale, bias));
        r.y = fmaxf(0.f, fmaf(bf2f(wsv[g2 * 2] >> 16),        scale, bias));
        r.z = fmaxf(0.f, fmaf(bf2f(wsv[g2 * 2 + 1] & 0xffff), scale, bias));
        r.w = fmaxf(0.f, fmaf(bf2f(wsv[g2 * 2 + 1] >> 16),    scale, bias));
        __builtin_nontemporal_store(r, (f32x4*)(dst + g2 * 4));
    }
}

extern "C" void kernel_launch(void* const* d_in, const int* in_sizes, int n_in,
                              void* d_out, int out_size, void* d_ws, size_t ws_size,
                              hipStream_t stream) {
    const float* xyz1  = (const float*)d_in[0];
    const float* xyz2  = (const float*)d_in[1];
    const float* p1    = (const float*)d_in[2];
    const float* p2    = (const float*)d_in[3];
    const float* W     = (const float*)d_in[4];
    const float* gamma = (const float*)d_in[5];
    const float* beta  = (const float*)d_in[6];
    float* out = (float*)d_out;
    char* ws = (char*)d_ws;
    if (ws_size < (size_t)WS_NEED) return;

    int*      idxw     = (int*)(ws + IDXW_OFF);
    uint16_t* ztb      = (uint16_t*)(ws + ZTB_OFF);
    uint16_t* y1       = (uint16_t*)(ws + Y1_OFF);
    uint16_t* y2       = (uint16_t*)(ws + Y2_OFF);
    float*    partials = (float*)(ws + PART_OFF);
    float*    sb       = (float*)(ws + SB_OFF);
    uint16_t* w1b      = (uint16_t*)(ws + W1B_OFF);
    uint16_t* w2b      = (uint16_t*)(ws + W2B_OFF);

    hipLaunchKernelGGL(k0_prep,    dim3(320),    dim3(256), 0, stream, W, w1b, w2b);
    hipLaunchKernelGGL(k1_threenn, dim3(16, 16), dim3(256), 0, stream, xyz1, xyz2, idxw);
    hipLaunchKernelGGL(k2_z,       dim3(16, 16), dim3(256), 0, stream, p2, w2b, ztb);
    hipLaunchKernelGGL(k2b,        dim3(2048),   dim3(256), 0, stream, p1, w1b, y1);
    hipLaunchKernelGGL(k3a,        dim3(512),    dim3(512), 0, stream, y1, ztb, idxw, y2, partials);
    hipLaunchKernelGGL(k3b,        dim3(1),      dim3(256), 0, stream, partials, gamma, beta, sb);
    hipLaunchKernelGGL(k3c,        dim3(4096),   dim3(256), 0, stream, y2, sb, out);
}

// Round 8
// 160.961 us; speedup vs baseline: 1.3605x; 1.3605x over previous
//
#include <hip/hip_runtime.h>
#include <stdint.h>

// PointNet Feature Propagation, MI355X.
//  K0 : W f32 -> w1b bf16 [256][64], w2b bf16 [256][256]
//  K1 : exact f32 3-NN + inverse-distance weights -> idxw [B][N][8]
//       (8 s-chunks x 128, 1 n/thread, 2048 blocks -> full occupancy)
//  K2 : ztb = W2 @ p2, bf16, o-blocked [b][og16][s1024][16o]
//  K2b: y1 = W1 @ p1, bf16, o-blocked [b][og16][n4096][16o]
//  K3a: y2 = y1 + sum_k w_k * ztb[idx_k]  (LDS-staged gather) -> bf16 + BN partials
//  K3b: partials -> per-channel scale/bias
//  K3c: y2 -> LDS transpose -> BN+ReLU -> d_out f32 [b][o][n]

#define B_   16
#define N_   4096
#define S_   1024
#define D1_  64
#define D2_  256
#define OC_  256

typedef __attribute__((ext_vector_type(8))) short bf16x8;
typedef __attribute__((ext_vector_type(4))) float f32x4;
typedef __attribute__((ext_vector_type(4))) unsigned int u32x4;
typedef __attribute__((ext_vector_type(2))) unsigned int u32x2;

// workspace layout (bytes)
#define IDXW_OFF 0u           // 2 MB
#define ZTB_OFF  2097152u     // 8 MB
#define Y1_OFF   10485760u    // 32 MB
#define Y2_OFF   44040192u    // 32 MB
#define PART_OFF 77594624u    // 64 KB
#define SB_OFF   77660160u    // 2 KB
#define W1B_OFF  77662208u    // 32 KB
#define W2B_OFF  77694976u    // 128 KB
#define WS_NEED  77826048u

__device__ __forceinline__ uint16_t f2bf(float f) {
    union { float f; uint32_t u; } v; v.f = f;
    uint32_t r = v.u + 0x7FFFu + ((v.u >> 16) & 1u);   // RNE
    return (uint16_t)(r >> 16);
}
__device__ __forceinline__ float bf2f(uint32_t h) {
    union { uint32_t u; float f; } v; v.u = h << 16;
    return v.f;
}

// ---------------- K0 ----------------
__global__ void k0_prep(const float* __restrict__ W,
                        uint16_t* __restrict__ w1b, uint16_t* __restrict__ w2b) {
    int e = blockIdx.x * 256 + threadIdx.x;
    if (e >= OC_ * 320) return;
    int o = e / 320, c = e % 320;
    uint16_t b = f2bf(W[e]);
    if (c < 64) w1b[o * 64 + c] = b;
    else        w2b[o * 256 + (c - 64)] = b;
}

// ---------------- K1: three_nn ----------------
#define INSERT(d, sidx, d0, d1, d2, i0, i1, i2) do {                      \
    bool ca = (d) < (d2); bool cb = (d) < (d1); bool cc = (d) < (d0);     \
    float _n1 = __builtin_amdgcn_fmed3f((d), (d0), (d1));                 \
    float _n2 = __builtin_amdgcn_fmed3f((d), (d1), (d2));                 \
    int _j2 = cb ? (i1) : (ca ? (sidx) : (i2));                           \
    int _j1 = cc ? (i0) : (cb ? (sidx) : (i1));                           \
    i0 = cc ? (sidx) : (i0);                                              \
    d0 = fminf((d), (d0)); d1 = _n1; d2 = _n2; i1 = _j1; i2 = _j2;        \
} while (0)

__global__ void __launch_bounds__(256, 8)
k1_threenn(const float* __restrict__ xyz1,
           const float* __restrict__ xyz2,
           int* __restrict__ idxw) {
    __shared__ float4 pts[8 * 129];     // 8 chunks of 128, +1 stagger
    int b  = blockIdx.y;
    int n0 = blockIdx.x * 32;
    int t  = threadIdx.x;

    for (int s = t; s < S_; s += 256) {
        const float* p = xyz2 + ((size_t)b * S_ + s) * 3;
        pts[(s >> 7) * 129 + (s & 127)] = make_float4(p[0], p[1], p[2], 0.f);
    }
    __syncthreads();

    int chunk = t & 7, nidx = t >> 3;   // 32 n-slots x 8 chunks
    int n = n0 + nidx;
    const float* q = xyz1 + ((size_t)b * N_ + n) * 3;
    float ax = q[0], ay = q[1], az = q[2];

    float d0 = 3.4e38f, d1 = 3.4e38f, d2 = 3.4e38f;
    int   i0 = 0, i1 = 0, i2 = 0;

    const float4* base = pts + chunk * 129;
    int sbase = chunk * 128;
    #pragma unroll 4
    for (int j = 0; j < 128; j++) {
        float4 qq = base[j];
        int s = sbase + j;
        float dx = ax - qq.x, dy = ay - qq.y, dz = az - qq.z;
        float d = fmaf(dz, dz, fmaf(dy, dy, dx * dx));
        INSERT(d, s, d0, d1, d2, i0, i1, i2);
    }
    // merge 8 chunk-results across lane bits 0..2 (ascending-s receiver wins ties)
    #pragma unroll
    for (int m = 1; m <= 4; m <<= 1) {
        float e0 = __shfl_xor(d0, m), e1 = __shfl_xor(d1, m), e2 = __shfl_xor(d2, m);
        int   g0 = __shfl_xor(i0, m), g1 = __shfl_xor(i1, m), g2 = __shfl_xor(i2, m);
        INSERT(e0, g0, d0, d1, d2, i0, i1, i2);
        INSERT(e1, g1, d0, d1, d2, i0, i1, i2);
        INSERT(e2, g2, d0, d1, d2, i0, i1, i2);
    }
    if (chunk == 0) {
        float r0 = 1.0f / (d0 + 1e-8f), r1 = 1.0f / (d1 + 1e-8f), r2 = 1.0f / (d2 + 1e-8f);
        float rs = r0 + r1 + r2;
        float* fw = (float*)idxw;
        int bb = (b * N_ + n) * 8;
        idxw[bb + 0] = i0; idxw[bb + 1] = i1; idxw[bb + 2] = i2;
        fw[bb + 4] = r0 / rs; fw[bb + 5] = r1 / rs; fw[bb + 6] = r2 / rs;
    }
}

// ---------------- K2: ztb = W2@p2, o-blocked bf16 ----------------
__global__ void k2_z(const float* __restrict__ p2, const uint16_t* __restrict__ w2b,
                     uint16_t* __restrict__ ztb) {
    __shared__ char smem[40960];
    uint16_t* a_t = (uint16_t*)smem;            // [64 s][64 c], 128B rows, swz <<4
    uint16_t* w_t = (uint16_t*)(smem + 8192);   // [256 o][64 c]
    int b = blockIdx.y, s0 = blockIdx.x * 64;
    int t = threadIdx.x, l = t & 63, w = t >> 6;   // 4 waves

    f32x4 acc[4][4] = {};   // [mi(s)][oj(o)]
    for (int ck = 0; ck < 4; ck++) {
        __syncthreads();
        {
            int sA = w * 16 + (l & 15);
            const float* p2b = p2 + ((size_t)b * D2_ + (size_t)ck * 64) * S_ + s0;
            #pragma unroll
            for (int j = 0; j < 8; j++) {
                int cp = (l >> 4) + 4 * j;
                float lo = p2b[(size_t)(2 * cp) * S_ + sA];
                float hi = p2b[(size_t)(2 * cp + 1) * S_ + sA];
                uint32_t pk = (uint32_t)f2bf(lo) | ((uint32_t)f2bf(hi) << 16);
                *(uint32_t*)((char*)a_t + sA * 128 + ((cp * 4) ^ ((sA & 7) << 4))) = pk;
            }
        }
        {
            int wp = t & 31, orow0 = t >> 5;
            #pragma unroll 4
            for (int jj = 0; jj < 32; jj++) {
                int o = orow0 + 8 * jj;
                uint32_t v = *(const uint32_t*)(w2b + (size_t)o * 256 + ck * 64 + 2 * wp);
                *(uint32_t*)((char*)w_t + o * 128 + ((wp * 4) ^ ((o & 7) << 4))) = v;
            }
        }
        __syncthreads();
        #pragma unroll
        for (int ks = 0; ks < 2; ks++) {
            bf16x8 a[4], bb[4];
            int co = ks * 32 + (l >> 4) * 8;
            #pragma unroll
            for (int mi = 0; mi < 4; mi++) {
                int s = mi * 16 + (l & 15);
                a[mi] = *(const bf16x8*)((const char*)a_t + s * 128 + ((co * 2) ^ ((s & 7) << 4)));
            }
            #pragma unroll
            for (int oj = 0; oj < 4; oj++) {
                int o = w * 64 + oj * 16 + (l & 15);
                bb[oj] = *(const bf16x8*)((const char*)w_t + o * 128 + ((co * 2) ^ ((o & 7) << 4)));
            }
            #pragma unroll
            for (int mi = 0; mi < 4; mi++)
                #pragma unroll
                for (int oj = 0; oj < 4; oj++)
                    acc[mi][oj] = __builtin_amdgcn_mfma_f32_16x16x32_bf16(
                        a[mi], bb[oj], acc[mi][oj], 0, 0, 0);
        }
    }
    __syncthreads();
    char* tz = smem;   // [64 s][512 B], swz <<5
    #pragma unroll
    for (int mi = 0; mi < 4; mi++)
        #pragma unroll
        for (int oj = 0; oj < 4; oj++)
            #pragma unroll
            for (int r = 0; r < 4; r++) {
                int sl = mi * 16 + (l >> 4) * 4 + r;
                int o  = w * 64 + oj * 16 + (l & 15);
                *(uint16_t*)(tz + sl * 512 + ((o * 2) ^ ((sl & 7) << 5))) = f2bf(acc[mi][oj][r]);
            }
    __syncthreads();
    {
        int og = t >> 4, rr = t & 15;
        uint16_t* zb = ztb + ((size_t)(b * 16 + og) * S_ + s0) * 16;
        #pragma unroll
        for (int k = 0; k < 4; k++) {
            int s = rr * 4 + k;
            u32x4 v0 = *(u32x4*)(tz + s * 512 + ((og * 32) ^ ((s & 7) << 5)));
            u32x4 v1 = *(u32x4*)(tz + s * 512 + (((og * 32) ^ ((s & 7) << 5)) | 16));
            __builtin_nontemporal_store(v0, (u32x4*)(zb + (size_t)s * 16));
            __builtin_nontemporal_store(v1, (u32x4*)(zb + (size_t)s * 16 + 8));
        }
    }
}

// ---------------- K2b: y1 = W1@p1, o-blocked bf16 ----------------
__global__ void __launch_bounds__(256, 4)
k2b(const float* __restrict__ p1, const uint16_t* __restrict__ w1b,
    uint16_t* __restrict__ y1) {
    int i = blockIdx.x;            // 2048
    int b = i >> 7, n0 = (i & 127) * 32;
    int t = threadIdx.x, l = t & 63, w = t >> 6;
    int oW = w * 64;
    __shared__ uint16_t pt[32 * 64];   // [n][c], 128B rows, swz <<4
    {
        int nn = t & 31;
        const float* p1b = p1 + (size_t)b * D1_ * N_ + n0;
        #pragma unroll
        for (int j = 0; j < 4; j++) {
            int cp = (t >> 5) + 8 * j;
            float lo = p1b[(size_t)(2 * cp) * N_ + nn];
            float hi = p1b[(size_t)(2 * cp + 1) * N_ + nn];
            uint32_t pk = (uint32_t)f2bf(lo) | ((uint32_t)f2bf(hi) << 16);
            *(uint32_t*)((char*)pt + nn * 128 + ((cp * 4) ^ ((nn & 7) << 4))) = pk;
        }
    }
    bf16x8 af[2][4];
    #pragma unroll
    for (int ks = 0; ks < 2; ks++)
        #pragma unroll
        for (int mi = 0; mi < 4; mi++) {
            int o = oW + mi * 16 + (l & 15);
            af[ks][mi] = *(const bf16x8*)(w1b + (size_t)o * 64 + ks * 32 + (l >> 4) * 8);
        }
    f32x4 acc[4][2] = {};   // [mi(o)][bj(n)]
    __syncthreads();
    #pragma unroll
    for (int ks = 0; ks < 2; ks++) {
        bf16x8 bf[2];
        int co = ks * 32 + (l >> 4) * 8;
        #pragma unroll
        for (int bj = 0; bj < 2; bj++) {
            int nn = bj * 16 + (l & 15);
            bf[bj] = *(const bf16x8*)((const char*)pt + nn * 128 + ((co * 2) ^ ((nn & 7) << 4)));
        }
        #pragma unroll
        for (int mi = 0; mi < 4; mi++)
            #pragma unroll
            for (int bj = 0; bj < 2; bj++)
                acc[mi][bj] = __builtin_amdgcn_mfma_f32_16x16x32_bf16(
                    af[ks][mi], bf[bj], acc[mi][bj], 0, 0, 0);
    }
    #pragma unroll
    for (int mi = 0; mi < 4; mi++) {
        int og = w * 4 + mi;
        uint16_t* yb = y1 + ((size_t)(b * 16 + og)) * N_ * 16;
        #pragma unroll
        for (int bj = 0; bj < 2; bj++) {
            int n = n0 + bj * 16 + (l & 15);
            int oo = (l >> 4) * 4;
            u32x2 v;
            v.x = (uint32_t)f2bf(acc[mi][bj][0]) | ((uint32_t)f2bf(acc[mi][bj][1]) << 16);
            v.y = (uint32_t)f2bf(acc[mi][bj][2]) | ((uint32_t)f2bf(acc[mi][bj][3]) << 16);
            __builtin_nontemporal_store(v, (u32x2*)(yb + (size_t)n * 16 + oo));
        }
    }
}

// ---------------- K3a: LDS-staged gather -> y2 bf16 + BN partials ----------------
__global__ void __launch_bounds__(512, 4)
k3a(const uint16_t* __restrict__ y1, const uint16_t* __restrict__ ztb,
    const int* __restrict__ idxw, uint16_t* __restrict__ y2,
    float* __restrict__ partials) {
    __shared__ char zsm[49152];          // [1024 s][48B] rows (32B used)
    __shared__ float red[8][16][2];
    int bi = blockIdx.x;                 // 512: b*32 + og*2 + nh
    int b = bi >> 5, og = (bi >> 1) & 15, nh = bi & 1;
    int u = threadIdx.x, l = u & 63, w = u >> 6;
    {
        const u32x4* src = (const u32x4*)(ztb + ((size_t)(b * 16 + og)) * S_ * 16);
        #pragma unroll
        for (int k = 0; k < 4; k++) {
            int g = k * 512 + u;
            u32x4 v = src[g];
            *(u32x4*)(zsm + (g >> 1) * 48 + (g & 1) * 16) = v;
        }
    }
    __syncthreads();
    int q = l >> 2, sub = l & 3;
    float s1l[4] = {0.f, 0.f, 0.f, 0.f}, s2l[4] = {0.f, 0.f, 0.f, 0.f};
    int nbase = nh * 2048 + w * 256;
    const uint16_t* y1b = y1 + ((size_t)(b * 16 + og)) * N_ * 16;
    uint16_t* y2b = y2 + ((size_t)(b * 16 + og)) * N_ * 16;
    for (int it = 0; it < 16; it++) {
        int n = nbase + it * 16 + q;
        u32x2 y1v = __builtin_nontemporal_load((const u32x2*)(y1b + (size_t)n * 16 + sub * 4));
        const int* ib = idxw + ((size_t)(b * N_ + n)) * 8;
        int4   iv = *(const int4*)ib;
        float4 wv = *((const float4*)ib + 1);
        u32x2 z0 = *(const u32x2*)(zsm + iv.x * 48 + sub * 8);
        u32x2 z1 = *(const u32x2*)(zsm + iv.y * 48 + sub * 8);
        u32x2 z2 = *(const u32x2*)(zsm + iv.z * 48 + sub * 8);
        float a0 = bf2f(y1v.x & 0xffff) + wv.x * bf2f(z0.x & 0xffff) + wv.y * bf2f(z1.x & 0xffff) + wv.z * bf2f(z2.x & 0xffff);
        float a1 = bf2f(y1v.x >> 16)    + wv.x * bf2f(z0.x >> 16)    + wv.y * bf2f(z1.x >> 16)    + wv.z * bf2f(z2.x >> 16);
        float a2 = bf2f(y1v.y & 0xffff) + wv.x * bf2f(z0.y & 0xffff) + wv.y * bf2f(z1.y & 0xffff) + wv.z * bf2f(z2.y & 0xffff);
        float a3 = bf2f(y1v.y >> 16)    + wv.x * bf2f(z0.y >> 16)    + wv.y * bf2f(z1.y >> 16)    + wv.z * bf2f(z2.y >> 16);
        s1l[0] += a0; s2l[0] += a0 * a0;
        s1l[1] += a1; s2l[1] += a1 * a1;
        s1l[2] += a2; s2l[2] += a2 * a2;
        s1l[3] += a3; s2l[3] += a3 * a3;
        u32x2 vv;
        vv.x = (uint32_t)f2bf(a0) | ((uint32_t)f2bf(a1) << 16);
        vv.y = (uint32_t)f2bf(a2) | ((uint32_t)f2bf(a3) << 16);
        __builtin_nontemporal_store(vv, (u32x2*)(y2b + (size_t)n * 16 + sub * 4));
    }
    #pragma unroll
    for (int m = 4; m <= 32; m <<= 1)
        #pragma unroll
        for (int j = 0; j < 4; j++) {
            s1l[j] += __shfl_xor(s1l[j], m);
            s2l[j] += __shfl_xor(s2l[j], m);
        }
    if (l < 4) {
        #pragma unroll
        for (int j = 0; j < 4; j++) {
            red[w][sub * 4 + j][0] = s1l[j];
            red[w][sub * 4 + j][1] = s2l[j];
        }
    }
    __syncthreads();
    if (u < 32) {
        int oi = u >> 1, st = u & 1;
        float s = 0.f;
        #pragma unroll
        for (int ww = 0; ww < 8; ww++) s += red[ww][oi][st];
        partials[(size_t)bi * 32 + oi * 2 + st] = s;
    }
}

// ---------------- K3b ----------------
__global__ void k3b(const float* __restrict__ partials, const float* __restrict__ gamma,
                    const float* __restrict__ beta, float* __restrict__ sb) {
    int o = threadIdx.x;           // 256
    int og = o >> 4, oo = o & 15;
    float a = 0.f, q = 0.f;
    for (int t = 0; t < 32; t++) {
        int bb = t >> 1, nh = t & 1;
        int bi = bb * 32 + og * 2 + nh;
        a += partials[(size_t)bi * 32 + oo * 2];
        q += partials[(size_t)bi * 32 + oo * 2 + 1];
    }
    float mean = a / 65536.0f;
    float var  = q / 65536.0f - mean * mean;
    float scale = gamma[o] * rsqrtf(var + 1e-5f);
    sb[o * 2] = scale;
    sb[o * 2 + 1] = beta[o] - mean * scale;
}

// ---------------- K3c: y2 -> LDS transpose -> BN+ReLU -> out ----------------
__global__ void __launch_bounds__(256, 8)
k3c(const uint16_t* __restrict__ y2, const float* __restrict__ sb,
    float* __restrict__ out) {
    __shared__ uint16_t ty[16 * 256];   // [16 o][256 n], byte XOR bit4 by (o&7)
    int bi = blockIdx.x;                // 4096: b*256 + og*16 + nc
    int b = bi >> 8, og = (bi >> 4) & 15, nc = bi & 15;
    int u = threadIdx.x;
    const uint16_t* src = y2 + (((size_t)(b * 16 + og)) * N_ + nc * 256) * 16;
    u32x4 va = __builtin_nontemporal_load((const u32x4*)(src + (size_t)u * 16));
    u32x4 vb = __builtin_nontemporal_load((const u32x4*)(src + (size_t)u * 16 + 8));
    uint32_t words[8] = {va.x, va.y, va.z, va.w, vb.x, vb.y, vb.z, vb.w};
    #pragma unroll
    for (int h = 0; h < 8; h++) {
        int o0 = h * 2, o1 = h * 2 + 1;
        *(uint16_t*)((char*)ty + o0 * 512 + ((u * 2) ^ ((o0 & 7) << 4))) = (uint16_t)(words[h] & 0xffff);
        *(uint16_t*)((char*)ty + o1 * 512 + ((u * 2) ^ ((o1 & 7) << 4))) = (uint16_t)(words[h] >> 16);
    }
    __syncthreads();
    int o = u >> 4, nb = (u & 15) * 16;
    int x = (o & 7) << 4;
    int basea = o * 512 + nb * 2;
    u32x4 lo = *(const u32x4*)((const char*)ty + (basea ^ x));
    u32x4 hi = *(const u32x4*)((const char*)ty + ((basea + 16) ^ x));
    int o_g = og * 16 + o;
    float scale = sb[o_g * 2], bias = sb[o_g * 2 + 1];
    float* dst = out + ((size_t)(b * OC_ + o_g)) * N_ + nc * 256 + nb;
    uint32_t wsv[8] = {lo.x, lo.y, lo.z, lo.w, hi.x, hi.y, hi.z, hi.w};
    #pragma unroll
    for (int g2 = 0; g2 < 4; g2++) {
        f32x4 r;
        r.x = fmaxf(0.f, fmaf(bf2f(wsv[g2 * 2] & 0xffff),     scale, bias));
        r.y = fmaxf(0.f, fmaf(bf2f(wsv[g2 * 2] >> 16),        scale, bias));
        r.z = fmaxf(0.f, fmaf(bf2f(wsv[g2 * 2 + 1] & 0xffff), scale, bias));
        r.w = fmaxf(0.f, fmaf(bf2f(wsv[g2 * 2 + 1] >> 16),    scale, bias));
        __builtin_nontemporal_store(r, (f32x4*)(dst + g2 * 4));
    }
}

extern "C" void kernel_launch(void* const* d_in, const int* in_sizes, int n_in,
                              void* d_out, int out_size, void* d_ws, size_t ws_size,
                              hipStream_t stream) {
    const float* xyz1  = (const float*)d_in[0];
    const float* xyz2  = (const float*)d_in[1];
    const float* p1    = (const float*)d_in[2];
    const float* p2    = (const float*)d_in[3];
    const float* W     = (const float*)d_in[4];
    const float* gamma = (const float*)d_in[5];
    const float* beta  = (const float*)d_in[6];
    float* out = (float*)d_out;
    char* ws = (char*)d_ws;
    if (ws_size < (size_t)WS_NEED) return;

    int*      idxw     = (int*)(ws + IDXW_OFF);
    uint16_t* ztb      = (uint16_t*)(ws + ZTB_OFF);
    uint16_t* y1       = (uint16_t*)(ws + Y1_OFF);
    uint16_t* y2       = (uint16_t*)(ws + Y2_OFF);
    float*    partials = (float*)(ws + PART_OFF);
    float*    sb       = (float*)(ws + SB_OFF);
    uint16_t* w1b      = (uint16_t*)(ws + W1B_OFF);
    uint16_t* w2b      = (uint16_t*)(ws + W2B_OFF);

    hipLaunchKernelGGL(k0_prep,    dim3(320),     dim3(256), 0, stream, W, w1b, w2b);
    hipLaunchKernelGGL(k1_threenn, dim3(128, 16), dim3(256), 0, stream, xyz1, xyz2, idxw);
    hipLaunchKernelGGL(k2_z,       dim3(16, 16),  dim3(256), 0, stream, p2, w2b, ztb);
    hipLaunchKernelGGL(k2b,        dim3(2048),    dim3(256), 0, stream, p1, w1b, y1);
    hipLaunchKernelGGL(k3a,        dim3(512),     dim3(512), 0, stream, y1, ztb, idxw, y2, partials);
    hipLaunchKernelGGL(k3b,        dim3(1),       dim3(256), 0, stream, partials, gamma, beta, sb);
    hipLaunchKernelGGL(k3c,        dim3(4096),    dim3(256), 0, stream, y2, sb, out);
}

// Round 9
// 123.114 us; speedup vs baseline: 1.7788x; 1.3074x over previous
//
#include <hip/hip_runtime.h>
#include <stdint.h>

// PointNet Feature Propagation, MI355X.
//  K0 : W f32 -> w1b bf16 [256][64], w2b bf16 [256][256]
//  K1 : exact f32 3-NN + inverse-distance weights -> idxw [B][N][8]
//  K2 : ztb = W2 @ p2, bf16, o-blocked [b][og16][s1024][16o]
//  K2b: y1 = W1 @ p1, bf16, o-blocked [b][og16][n4096][16o]
//  K3a: y2 = y1 + sum_k w_k * ztb[idx_k]  (LDS-staged gather) -> bf16 + BN partials
//  K3b: partials -> per-channel scale/bias
//  K3c: y2 -> LDS transpose -> BN+ReLU -> d_out f32 (lane-contiguous 256B stores)

#define B_   16
#define N_   4096
#define S_   1024
#define D1_  64
#define D2_  256
#define OC_  256

typedef __attribute__((ext_vector_type(8))) short bf16x8;
typedef __attribute__((ext_vector_type(4))) float f32x4;
typedef __attribute__((ext_vector_type(4))) unsigned int u32x4;
typedef __attribute__((ext_vector_type(2))) unsigned int u32x2;

// workspace layout (bytes)
#define IDXW_OFF 0u           // 2 MB
#define ZTB_OFF  2097152u     // 8 MB
#define Y1_OFF   10485760u    // 32 MB
#define Y2_OFF   44040192u    // 32 MB
#define PART_OFF 77594624u    // 64 KB
#define SB_OFF   77660160u    // 2 KB
#define W1B_OFF  77662208u    // 32 KB
#define W2B_OFF  77694976u    // 128 KB
#define WS_NEED  77826048u

__device__ __forceinline__ uint16_t f2bf(float f) {
    union { float f; uint32_t u; } v; v.f = f;
    uint32_t r = v.u + 0x7FFFu + ((v.u >> 16) & 1u);   // RNE
    return (uint16_t)(r >> 16);
}
__device__ __forceinline__ float bf2f(uint32_t h) {
    union { uint32_t u; float f; } v; v.u = h << 16;
    return v.f;
}

// ---------------- K0 ----------------
__global__ void k0_prep(const float* __restrict__ W,
                        uint16_t* __restrict__ w1b, uint16_t* __restrict__ w2b) {
    int e = blockIdx.x * 256 + threadIdx.x;
    if (e >= OC_ * 320) return;
    int o = e / 320, c = e % 320;
    uint16_t b = f2bf(W[e]);
    if (c < 64) w1b[o * 64 + c] = b;
    else        w2b[o * 256 + (c - 64)] = b;
}

// ---------------- K1: three_nn ----------------
#define INSERT(d, sidx, d0, d1, d2, i0, i1, i2) do {                      \
    bool ca = (d) < (d2); bool cb = (d) < (d1); bool cc = (d) < (d0);     \
    float _n1 = __builtin_amdgcn_fmed3f((d), (d0), (d1));                 \
    float _n2 = __builtin_amdgcn_fmed3f((d), (d1), (d2));                 \
    int _j2 = cb ? (i1) : (ca ? (sidx) : (i2));                           \
    int _j1 = cc ? (i0) : (cb ? (sidx) : (i1));                           \
    i0 = cc ? (sidx) : (i0);                                              \
    d0 = fminf((d), (d0)); d1 = _n1; d2 = _n2; i1 = _j1; i2 = _j2;        \
} while (0)

__global__ void __launch_bounds__(256, 8)
k1_threenn(const float* __restrict__ xyz1,
           const float* __restrict__ xyz2,
           int* __restrict__ idxw) {
    __shared__ float4 pts[8 * 129];     // 8 chunks of 128, +1 stagger
    int b  = blockIdx.y;
    int n0 = blockIdx.x * 32;
    int t  = threadIdx.x;

    for (int s = t; s < S_; s += 256) {
        const float* p = xyz2 + ((size_t)b * S_ + s) * 3;
        pts[(s >> 7) * 129 + (s & 127)] = make_float4(p[0], p[1], p[2], 0.f);
    }
    __syncthreads();

    int chunk = t & 7, nidx = t >> 3;   // 32 n-slots x 8 chunks
    int n = n0 + nidx;
    const float* q = xyz1 + ((size_t)b * N_ + n) * 3;
    float ax = q[0], ay = q[1], az = q[2];

    float d0 = 3.4e38f, d1 = 3.4e38f, d2 = 3.4e38f;
    int   i0 = 0, i1 = 0, i2 = 0;

    const float4* base = pts + chunk * 129;
    int sbase = chunk * 128;
    #pragma unroll 4
    for (int j = 0; j < 128; j++) {
        float4 qq = base[j];
        int s = sbase + j;
        float dx = ax - qq.x, dy = ay - qq.y, dz = az - qq.z;
        float d = fmaf(dz, dz, fmaf(dy, dy, dx * dx));
        INSERT(d, s, d0, d1, d2, i0, i1, i2);
    }
    #pragma unroll
    for (int m = 1; m <= 4; m <<= 1) {
        float e0 = __shfl_xor(d0, m), e1 = __shfl_xor(d1, m), e2 = __shfl_xor(d2, m);
        int   g0 = __shfl_xor(i0, m), g1 = __shfl_xor(i1, m), g2 = __shfl_xor(i2, m);
        INSERT(e0, g0, d0, d1, d2, i0, i1, i2);
        INSERT(e1, g1, d0, d1, d2, i0, i1, i2);
        INSERT(e2, g2, d0, d1, d2, i0, i1, i2);
    }
    if (chunk == 0) {
        float r0 = 1.0f / (d0 + 1e-8f), r1 = 1.0f / (d1 + 1e-8f), r2 = 1.0f / (d2 + 1e-8f);
        float rs = r0 + r1 + r2;
        float* fw = (float*)idxw;
        int bb = (b * N_ + n) * 8;
        idxw[bb + 0] = i0; idxw[bb + 1] = i1; idxw[bb + 2] = i2;
        fw[bb + 4] = r0 / rs; fw[bb + 5] = r1 / rs; fw[bb + 6] = r2 / rs;
    }
}

// ---------------- K2: ztb = W2@p2, o-blocked bf16 ----------------
__global__ void k2_z(const float* __restrict__ p2, const uint16_t* __restrict__ w2b,
                     uint16_t* __restrict__ ztb) {
    __shared__ char smem[40960];
    uint16_t* a_t = (uint16_t*)smem;            // [64 s][64 c], 128B rows, swz <<4
    uint16_t* w_t = (uint16_t*)(smem + 8192);   // [256 o][64 c]
    int b = blockIdx.y, s0 = blockIdx.x * 64;
    int t = threadIdx.x, l = t & 63, w = t >> 6;   // 4 waves

    f32x4 acc[4][4] = {};   // [mi(s)][oj(o)]
    for (int ck = 0; ck < 4; ck++) {
        __syncthreads();
        {
            int sA = w * 16 + (l & 15);
            const float* p2b = p2 + ((size_t)b * D2_ + (size_t)ck * 64) * S_ + s0;
            #pragma unroll
            for (int j = 0; j < 8; j++) {
                int cp = (l >> 4) + 4 * j;
                float lo = p2b[(size_t)(2 * cp) * S_ + sA];
                float hi = p2b[(size_t)(2 * cp + 1) * S_ + sA];
                uint32_t pk = (uint32_t)f2bf(lo) | ((uint32_t)f2bf(hi) << 16);
                *(uint32_t*)((char*)a_t + sA * 128 + ((cp * 4) ^ ((sA & 7) << 4))) = pk;
            }
        }
        {
            int wp = t & 31, orow0 = t >> 5;
            #pragma unroll 4
            for (int jj = 0; jj < 32; jj++) {
                int o = orow0 + 8 * jj;
                uint32_t v = *(const uint32_t*)(w2b + (size_t)o * 256 + ck * 64 + 2 * wp);
                *(uint32_t*)((char*)w_t + o * 128 + ((wp * 4) ^ ((o & 7) << 4))) = v;
            }
        }
        __syncthreads();
        #pragma unroll
        for (int ks = 0; ks < 2; ks++) {
            bf16x8 a[4], bb[4];
            int co = ks * 32 + (l >> 4) * 8;
            #pragma unroll
            for (int mi = 0; mi < 4; mi++) {
                int s = mi * 16 + (l & 15);
                a[mi] = *(const bf16x8*)((const char*)a_t + s * 128 + ((co * 2) ^ ((s & 7) << 4)));
            }
            #pragma unroll
            for (int oj = 0; oj < 4; oj++) {
                int o = w * 64 + oj * 16 + (l & 15);
                bb[oj] = *(const bf16x8*)((const char*)w_t + o * 128 + ((co * 2) ^ ((o & 7) << 4)));
            }
            #pragma unroll
            for (int mi = 0; mi < 4; mi++)
                #pragma unroll
                for (int oj = 0; oj < 4; oj++)
                    acc[mi][oj] = __builtin_amdgcn_mfma_f32_16x16x32_bf16(
                        a[mi], bb[oj], acc[mi][oj], 0, 0, 0);
        }
    }
    __syncthreads();
    char* tz = smem;   // [64 s][512 B], swz <<5
    #pragma unroll
    for (int mi = 0; mi < 4; mi++)
        #pragma unroll
        for (int oj = 0; oj < 4; oj++)
            #pragma unroll
            for (int r = 0; r < 4; r++) {
                int sl = mi * 16 + (l >> 4) * 4 + r;
                int o  = w * 64 + oj * 16 + (l & 15);
                *(uint16_t*)(tz + sl * 512 + ((o * 2) ^ ((sl & 7) << 5))) = f2bf(acc[mi][oj][r]);
            }
    __syncthreads();
    {
        int og = t >> 4, rr = t & 15;
        uint16_t* zb = ztb + ((size_t)(b * 16 + og) * S_ + s0) * 16;
        #pragma unroll
        for (int k = 0; k < 4; k++) {
            int s = rr * 4 + k;
            u32x4 v0 = *(u32x4*)(tz + s * 512 + ((og * 32) ^ ((s & 7) << 5)));
            u32x4 v1 = *(u32x4*)(tz + s * 512 + (((og * 32) ^ ((s & 7) << 5)) | 16));
            __builtin_nontemporal_store(v0, (u32x4*)(zb + (size_t)s * 16));
            __builtin_nontemporal_store(v1, (u32x4*)(zb + (size_t)s * 16 + 8));
        }
    }
}

// ---------------- K2b: y1 = W1@p1, o-blocked bf16 ----------------
__global__ void __launch_bounds__(256, 4)
k2b(const float* __restrict__ p1, const uint16_t* __restrict__ w1b,
    uint16_t* __restrict__ y1) {
    int i = blockIdx.x;            // 2048
    int b = i >> 7, n0 = (i & 127) * 32;
    int t = threadIdx.x, l = t & 63, w = t >> 6;
    int oW = w * 64;
    __shared__ uint16_t pt[32 * 64];   // [n][c], 128B rows, swz <<4
    {
        int nn = t & 31;
        const float* p1b = p1 + (size_t)b * D1_ * N_ + n0;
        #pragma unroll
        for (int j = 0; j < 4; j++) {
            int cp = (t >> 5) + 8 * j;
            float lo = p1b[(size_t)(2 * cp) * N_ + nn];
            float hi = p1b[(size_t)(2 * cp + 1) * N_ + nn];
            uint32_t pk = (uint32_t)f2bf(lo) | ((uint32_t)f2bf(hi) << 16);
            *(uint32_t*)((char*)pt + nn * 128 + ((cp * 4) ^ ((nn & 7) << 4))) = pk;
        }
    }
    bf16x8 af[2][4];
    #pragma unroll
    for (int ks = 0; ks < 2; ks++)
        #pragma unroll
        for (int mi = 0; mi < 4; mi++) {
            int o = oW + mi * 16 + (l & 15);
            af[ks][mi] = *(const bf16x8*)(w1b + (size_t)o * 64 + ks * 32 + (l >> 4) * 8);
        }
    f32x4 acc[4][2] = {};   // [mi(o)][bj(n)]
    __syncthreads();
    #pragma unroll
    for (int ks = 0; ks < 2; ks++) {
        bf16x8 bf[2];
        int co = ks * 32 + (l >> 4) * 8;
        #pragma unroll
        for (int bj = 0; bj < 2; bj++) {
            int nn = bj * 16 + (l & 15);
            bf[bj] = *(const bf16x8*)((const char*)pt + nn * 128 + ((co * 2) ^ ((nn & 7) << 4)));
        }
        #pragma unroll
        for (int mi = 0; mi < 4; mi++)
            #pragma unroll
            for (int bj = 0; bj < 2; bj++)
                acc[mi][bj] = __builtin_amdgcn_mfma_f32_16x16x32_bf16(
                    af[ks][mi], bf[bj], acc[mi][bj], 0, 0, 0);
    }
    #pragma unroll
    for (int mi = 0; mi < 4; mi++) {
        int og = w * 4 + mi;
        uint16_t* yb = y1 + ((size_t)(b * 16 + og)) * N_ * 16;
        #pragma unroll
        for (int bj = 0; bj < 2; bj++) {
            int n = n0 + bj * 16 + (l & 15);
            int oo = (l >> 4) * 4;
            u32x2 v;
            v.x = (uint32_t)f2bf(acc[mi][bj][0]) | ((uint32_t)f2bf(acc[mi][bj][1]) << 16);
            v.y = (uint32_t)f2bf(acc[mi][bj][2]) | ((uint32_t)f2bf(acc[mi][bj][3]) << 16);
            __builtin_nontemporal_store(v, (u32x2*)(yb + (size_t)n * 16 + oo));
        }
    }
}

// ---------------- K3a: LDS-staged gather -> y2 bf16 + BN partials ----------------
__global__ void __launch_bounds__(512, 4)
k3a(const uint16_t* __restrict__ y1, const uint16_t* __restrict__ ztb,
    const int* __restrict__ idxw, uint16_t* __restrict__ y2,
    float* __restrict__ partials) {
    __shared__ char zsm[49152];          // [1024 s][48B] rows (32B used)
    __shared__ float red[8][16][2];
    int bi = blockIdx.x;                 // 512: b*32 + og*2 + nh
    int b = bi >> 5, og = (bi >> 1) & 15, nh = bi & 1;
    int u = threadIdx.x, l = u & 63, w = u >> 6;
    {
        const u32x4* src = (const u32x4*)(ztb + ((size_t)(b * 16 + og)) * S_ * 16);
        #pragma unroll
        for (int k = 0; k < 4; k++) {
            int g = k * 512 + u;
            u32x4 v = src[g];
            *(u32x4*)(zsm + (g >> 1) * 48 + (g & 1) * 16) = v;
        }
    }
    __syncthreads();
    int q = l >> 2, sub = l & 3;
    float s1l[4] = {0.f, 0.f, 0.f, 0.f}, s2l[4] = {0.f, 0.f, 0.f, 0.f};
    int nbase = nh * 2048 + w * 256;
    const uint16_t* y1b = y1 + ((size_t)(b * 16 + og)) * N_ * 16;
    uint16_t* y2b = y2 + ((size_t)(b * 16 + og)) * N_ * 16;
    for (int it = 0; it < 16; it++) {
        int n = nbase + it * 16 + q;
        u32x2 y1v = __builtin_nontemporal_load((const u32x2*)(y1b + (size_t)n * 16 + sub * 4));
        const int* ib = idxw + ((size_t)(b * N_ + n)) * 8;
        int4   iv = *(const int4*)ib;
        float4 wv = *((const float4*)ib + 1);
        u32x2 z0 = *(const u32x2*)(zsm + iv.x * 48 + sub * 8);
        u32x2 z1 = *(const u32x2*)(zsm + iv.y * 48 + sub * 8);
        u32x2 z2 = *(const u32x2*)(zsm + iv.z * 48 + sub * 8);
        float a0 = bf2f(y1v.x & 0xffff) + wv.x * bf2f(z0.x & 0xffff) + wv.y * bf2f(z1.x & 0xffff) + wv.z * bf2f(z2.x & 0xffff);
        float a1 = bf2f(y1v.x >> 16)    + wv.x * bf2f(z0.x >> 16)    + wv.y * bf2f(z1.x >> 16)    + wv.z * bf2f(z2.x >> 16);
        float a2 = bf2f(y1v.y & 0xffff) + wv.x * bf2f(z0.y & 0xffff) + wv.y * bf2f(z1.y & 0xffff) + wv.z * bf2f(z2.y & 0xffff);
        float a3 = bf2f(y1v.y >> 16)    + wv.x * bf2f(z0.y >> 16)    + wv.y * bf2f(z1.y >> 16)    + wv.z * bf2f(z2.y >> 16);
        s1l[0] += a0; s2l[0] += a0 * a0;
        s1l[1] += a1; s2l[1] += a1 * a1;
        s1l[2] += a2; s2l[2] += a2 * a2;
        s1l[3] += a3; s2l[3] += a3 * a3;
        u32x2 vv;
        vv.x = (uint32_t)f2bf(a0) | ((uint32_t)f2bf(a1) << 16);
        vv.y = (uint32_t)f2bf(a2) | ((uint32_t)f2bf(a3) << 16);
        __builtin_nontemporal_store(vv, (u32x2*)(y2b + (size_t)n * 16 + sub * 4));
    }
    #pragma unroll
    for (int m = 4; m <= 32; m <<= 1)
        #pragma unroll
        for (int j = 0; j < 4; j++) {
            s1l[j] += __shfl_xor(s1l[j], m);
            s2l[j] += __shfl_xor(s2l[j], m);
        }
    if (l < 4) {
        #pragma unroll
        for (int j = 0; j < 4; j++) {
            red[w][sub * 4 + j][0] = s1l[j];
            red[w][sub * 4 + j][1] = s2l[j];
        }
    }
    __syncthreads();
    if (u < 32) {
        int oi = u >> 1, st = u & 1;
        float s = 0.f;
        #pragma unroll
        for (int ww = 0; ww < 8; ww++) s += red[ww][oi][st];
        partials[(size_t)bi * 32 + oi * 2 + st] = s;
    }
}

// ---------------- K3b ----------------
__global__ void k3b(const float* __restrict__ partials, const float* __restrict__ gamma,
                    const float* __restrict__ beta, float* __restrict__ sb) {
    int o = threadIdx.x;           // 256
    int og = o >> 4, oo = o & 15;
    float a = 0.f, q = 0.f;
    for (int t = 0; t < 32; t++) {
        int bb = t >> 1, nh = t & 1;
        int bi = bb * 32 + og * 2 + nh;
        a += partials[(size_t)bi * 32 + oo * 2];
        q += partials[(size_t)bi * 32 + oo * 2 + 1];
    }
    float mean = a / 65536.0f;
    float var  = q / 65536.0f - mean * mean;
    float scale = gamma[o] * rsqrtf(var + 1e-5f);
    sb[o * 2] = scale;
    sb[o * 2 + 1] = beta[o] - mean * scale;
}

// ---------------- K3c: y2 -> LDS transpose -> BN+ReLU -> out ----------------
// store phase: lane k=u&15 handles n = g2*64 + k*4 (16B/lane, 256B contiguous per
// 16-lane group per instruction) -- fixes the 64B-strided partial-line NT writes.
__global__ void __launch_bounds__(256, 8)
k3c(const uint16_t* __restrict__ y2, const float* __restrict__ sb,
    float* __restrict__ out) {
    __shared__ uint16_t ty[16 * 256];   // [16 o][256 n] bf16, byte XOR bit4-6 by (o&7)
    int bi = blockIdx.x;                // 4096: b*256 + og*16 + nc
    int b = bi >> 8, og = (bi >> 4) & 15, nc = bi & 15;
    int u = threadIdx.x;
    const uint16_t* src = y2 + (((size_t)(b * 16 + og)) * N_ + nc * 256) * 16;
    u32x4 va = __builtin_nontemporal_load((const u32x4*)(src + (size_t)u * 16));
    u32x4 vb = __builtin_nontemporal_load((const u32x4*)(src + (size_t)u * 16 + 8));
    uint32_t words[8] = {va.x, va.y, va.z, va.w, vb.x, vb.y, vb.z, vb.w};
    #pragma unroll
    for (int h = 0; h < 8; h++) {
        int o0 = h * 2, o1 = h * 2 + 1;
        *(uint16_t*)((char*)ty + o0 * 512 + ((u * 2) ^ ((o0 & 7) << 4))) = (uint16_t)(words[h] & 0xffff);
        *(uint16_t*)((char*)ty + o1 * 512 + ((u * 2) ^ ((o1 & 7) << 4))) = (uint16_t)(words[h] >> 16);
    }
    __syncthreads();
    int o = u >> 4, k = u & 15;
    int x = (o & 7) << 4;
    int o_g = og * 16 + o;
    float scale = sb[o_g * 2], bias = sb[o_g * 2 + 1];
    float* dst = out + ((size_t)(b * OC_ + o_g)) * N_ + nc * 256;
    #pragma unroll
    for (int g2 = 0; g2 < 4; g2++) {
        // 4 bf16 (8B) for n = g2*64 + k*4 .. +3
        uint64_t z = *(const uint64_t*)((const char*)ty + o * 512 + ((g2 * 128 + k * 8) ^ x));
        f32x4 r;
        r.x = fmaxf(0.f, fmaf(bf2f((uint32_t)(z       ) & 0xffff), scale, bias));
        r.y = fmaxf(0.f, fmaf(bf2f((uint32_t)(z >> 16 ) & 0xffff), scale, bias));
        r.z = fmaxf(0.f, fmaf(bf2f((uint32_t)(z >> 32 ) & 0xffff), scale, bias));
        r.w = fmaxf(0.f, fmaf(bf2f((uint32_t)(z >> 48 ) & 0xffff), scale, bias));
        __builtin_nontemporal_store(r, (f32x4*)(dst + g2 * 64 + k * 4));
    }
}

extern "C" void kernel_launch(void* const* d_in, const int* in_sizes, int n_in,
                              void* d_out, int out_size, void* d_ws, size_t ws_size,
                              hipStream_t stream) {
    const float* xyz1  = (const float*)d_in[0];
    const float* xyz2  = (const float*)d_in[1];
    const float* p1    = (const float*)d_in[2];
    const float* p2    = (const float*)d_in[3];
    const float* W     = (const float*)d_in[4];
    const float* gamma = (const float*)d_in[5];
    const float* beta  = (const float*)d_in[6];
    float* out = (float*)d_out;
    char* ws = (char*)d_ws;
    if (ws_size < (size_t)WS_NEED) return;

    int*      idxw     = (int*)(ws + IDXW_OFF);
    uint16_t* ztb      = (uint16_t*)(ws + ZTB_OFF);
    uint16_t* y1       = (uint16_t*)(ws + Y1_OFF);
    uint16_t* y2       = (uint16_t*)(ws + Y2_OFF);
    float*    partials = (float*)(ws + PART_OFF);
    float*    sb       = (float*)(ws + SB_OFF);
    uint16_t* w1b      = (uint16_t*)(ws + W1B_OFF);
    uint16_t* w2b      = (uint16_t*)(ws + W2B_OFF);

    hipLaunchKernelGGL(k0_prep,    dim3(320),     dim3(256), 0, stream, W, w1b, w2b);
    hipLaunchKernelGGL(k1_threenn, dim3(128, 16), dim3(256), 0, stream, xyz1, xyz2, idxw);
    hipLaunchKernelGGL(k2_z,       dim3(16, 16),  dim3(256), 0, stream, p2, w2b, ztb);
    hipLaunchKernelGGL(k2b,        dim3(2048),    dim3(256), 0, stream, p1, w1b, y1);
    hipLaunchKernelGGL(k3a,        dim3(512),     dim3(512), 0, stream, y1, ztb, idxw, y2, partials);
    hipLaunchKernelGGL(k3b,        dim3(1),       dim3(256), 0, stream, partials, gamma, beta, sb);
    hipLaunchKernelGGL(k3c,        dim3(4096),    dim3(256), 0, stream, y2, sb, out);
}

// Round 10
// 122.000 us; speedup vs baseline: 1.7950x; 1.0091x over previous
//
#include <hip/hip_runtime.h>
#include <stdint.h>

// PointNet Feature Propagation, MI355X.
//  K0 : W f32 -> w1b bf16 [256][64], w2b bf16 [256][256]
//  K1 : exact f32 3-NN + inverse-distance weights -> idxw [B][N][8]
//  K2 : ztb = W2 @ p2, bf16, o-blocked [b][og16][s1024][16o]
//  K2b: y1 = W1 @ p1, bf16, o-blocked [b][og16][n4096][16o]
//  K3a: y2 = y1 + sum_k w_k * ztb[idx_k]  (LDS-staged gather, 1024thr/100% occ) + BN partials
//  K3c: y2 -> LDS transpose -> (stats from partials) BN+ReLU -> d_out f32

#define B_   16
#define N_   4096
#define S_   1024
#define D1_  64
#define D2_  256
#define OC_  256

typedef __attribute__((ext_vector_type(8))) short bf16x8;
typedef __attribute__((ext_vector_type(4))) float f32x4;
typedef __attribute__((ext_vector_type(4))) unsigned int u32x4;
typedef __attribute__((ext_vector_type(2))) unsigned int u32x2;

// workspace layout (bytes)
#define IDXW_OFF 0u           // 2 MB
#define ZTB_OFF  2097152u     // 8 MB
#define Y1_OFF   10485760u    // 32 MB
#define Y2_OFF   44040192u    // 32 MB
#define PART_OFF 77594624u    // 64 KB
#define W1B_OFF  77662208u    // 32 KB
#define W2B_OFF  77694976u    // 128 KB
#define WS_NEED  77826048u

__device__ __forceinline__ uint16_t f2bf(float f) {
    union { float f; uint32_t u; } v; v.f = f;
    uint32_t r = v.u + 0x7FFFu + ((v.u >> 16) & 1u);   // RNE
    return (uint16_t)(r >> 16);
}
__device__ __forceinline__ float bf2f(uint32_t h) {
    union { uint32_t u; float f; } v; v.u = h << 16;
    return v.f;
}

// ---------------- K0 ----------------
__global__ void k0_prep(const float* __restrict__ W,
                        uint16_t* __restrict__ w1b, uint16_t* __restrict__ w2b) {
    int e = blockIdx.x * 256 + threadIdx.x;
    if (e >= OC_ * 320) return;
    int o = e / 320, c = e % 320;
    uint16_t b = f2bf(W[e]);
    if (c < 64) w1b[o * 64 + c] = b;
    else        w2b[o * 256 + (c - 64)] = b;
}

// ---------------- K1: three_nn ----------------
#define INSERT(d, sidx, d0, d1, d2, i0, i1, i2) do {                      \
    bool ca = (d) < (d2); bool cb = (d) < (d1); bool cc = (d) < (d0);     \
    float _n1 = __builtin_amdgcn_fmed3f((d), (d0), (d1));                 \
    float _n2 = __builtin_amdgcn_fmed3f((d), (d1), (d2));                 \
    int _j2 = cb ? (i1) : (ca ? (sidx) : (i2));                           \
    int _j1 = cc ? (i0) : (cb ? (sidx) : (i1));                           \
    i0 = cc ? (sidx) : (i0);                                              \
    d0 = fminf((d), (d0)); d1 = _n1; d2 = _n2; i1 = _j1; i2 = _j2;        \
} while (0)

__global__ void __launch_bounds__(256, 8)
k1_threenn(const float* __restrict__ xyz1,
           const float* __restrict__ xyz2,
           int* __restrict__ idxw) {
    __shared__ float4 pts[8 * 129];     // 8 chunks of 128, +1 stagger
    int b  = blockIdx.y;
    int n0 = blockIdx.x * 32;
    int t  = threadIdx.x;

    for (int s = t; s < S_; s += 256) {
        const float* p = xyz2 + ((size_t)b * S_ + s) * 3;
        pts[(s >> 7) * 129 + (s & 127)] = make_float4(p[0], p[1], p[2], 0.f);
    }
    __syncthreads();

    int chunk = t & 7, nidx = t >> 3;   // 32 n-slots x 8 chunks
    int n = n0 + nidx;
    const float* q = xyz1 + ((size_t)b * N_ + n) * 3;
    float ax = q[0], ay = q[1], az = q[2];

    float d0 = 3.4e38f, d1 = 3.4e38f, d2 = 3.4e38f;
    int   i0 = 0, i1 = 0, i2 = 0;

    const float4* base = pts + chunk * 129;
    int sbase = chunk * 128;
    #pragma unroll 4
    for (int j = 0; j < 128; j++) {
        float4 qq = base[j];
        int s = sbase + j;
        float dx = ax - qq.x, dy = ay - qq.y, dz = az - qq.z;
        float d = fmaf(dz, dz, fmaf(dy, dy, dx * dx));
        INSERT(d, s, d0, d1, d2, i0, i1, i2);
    }
    #pragma unroll
    for (int m = 1; m <= 4; m <<= 1) {
        float e0 = __shfl_xor(d0, m), e1 = __shfl_xor(d1, m), e2 = __shfl_xor(d2, m);
        int   g0 = __shfl_xor(i0, m), g1 = __shfl_xor(i1, m), g2 = __shfl_xor(i2, m);
        INSERT(e0, g0, d0, d1, d2, i0, i1, i2);
        INSERT(e1, g1, d0, d1, d2, i0, i1, i2);
        INSERT(e2, g2, d0, d1, d2, i0, i1, i2);
    }
    if (chunk == 0) {
        float r0 = 1.0f / (d0 + 1e-8f), r1 = 1.0f / (d1 + 1e-8f), r2 = 1.0f / (d2 + 1e-8f);
        float rs = r0 + r1 + r2;
        float* fw = (float*)idxw;
        int bb = (b * N_ + n) * 8;
        idxw[bb + 0] = i0; idxw[bb + 1] = i1; idxw[bb + 2] = i2;
        fw[bb + 4] = r0 / rs; fw[bb + 5] = r1 / rs; fw[bb + 6] = r2 / rs;
    }
}

// ---------------- K2: ztb = W2@p2, o-blocked bf16 ----------------
__global__ void k2_z(const float* __restrict__ p2, const uint16_t* __restrict__ w2b,
                     uint16_t* __restrict__ ztb) {
    __shared__ char smem[40960];
    uint16_t* a_t = (uint16_t*)smem;            // [64 s][64 c], 128B rows, swz <<4
    uint16_t* w_t = (uint16_t*)(smem + 8192);   // [256 o][64 c]
    int b = blockIdx.y, s0 = blockIdx.x * 64;
    int t = threadIdx.x, l = t & 63, w = t >> 6;   // 4 waves

    f32x4 acc[4][4] = {};   // [mi(s)][oj(o)]
    for (int ck = 0; ck < 4; ck++) {
        __syncthreads();
        {
            int sA = w * 16 + (l & 15);
            const float* p2b = p2 + ((size_t)b * D2_ + (size_t)ck * 64) * S_ + s0;
            #pragma unroll
            for (int j = 0; j < 8; j++) {
                int cp = (l >> 4) + 4 * j;
                float lo = p2b[(size_t)(2 * cp) * S_ + sA];
                float hi = p2b[(size_t)(2 * cp + 1) * S_ + sA];
                uint32_t pk = (uint32_t)f2bf(lo) | ((uint32_t)f2bf(hi) << 16);
                *(uint32_t*)((char*)a_t + sA * 128 + ((cp * 4) ^ ((sA & 7) << 4))) = pk;
            }
        }
        {
            int wp = t & 31, orow0 = t >> 5;
            #pragma unroll 4
            for (int jj = 0; jj < 32; jj++) {
                int o = orow0 + 8 * jj;
                uint32_t v = *(const uint32_t*)(w2b + (size_t)o * 256 + ck * 64 + 2 * wp);
                *(uint32_t*)((char*)w_t + o * 128 + ((wp * 4) ^ ((o & 7) << 4))) = v;
            }
        }
        __syncthreads();
        #pragma unroll
        for (int ks = 0; ks < 2; ks++) {
            bf16x8 a[4], bb[4];
            int co = ks * 32 + (l >> 4) * 8;
            #pragma unroll
            for (int mi = 0; mi < 4; mi++) {
                int s = mi * 16 + (l & 15);
                a[mi] = *(const bf16x8*)((const char*)a_t + s * 128 + ((co * 2) ^ ((s & 7) << 4)));
            }
            #pragma unroll
            for (int oj = 0; oj < 4; oj++) {
                int o = w * 64 + oj * 16 + (l & 15);
                bb[oj] = *(const bf16x8*)((const char*)w_t + o * 128 + ((co * 2) ^ ((o & 7) << 4)));
            }
            #pragma unroll
            for (int mi = 0; mi < 4; mi++)
                #pragma unroll
                for (int oj = 0; oj < 4; oj++)
                    acc[mi][oj] = __builtin_amdgcn_mfma_f32_16x16x32_bf16(
                        a[mi], bb[oj], acc[mi][oj], 0, 0, 0);
        }
    }
    __syncthreads();
    char* tz = smem;   // [64 s][512 B], swz <<5
    #pragma unroll
    for (int mi = 0; mi < 4; mi++)
        #pragma unroll
        for (int oj = 0; oj < 4; oj++)
            #pragma unroll
            for (int r = 0; r < 4; r++) {
                int sl = mi * 16 + (l >> 4) * 4 + r;
                int o  = w * 64 + oj * 16 + (l & 15);
                *(uint16_t*)(tz + sl * 512 + ((o * 2) ^ ((sl & 7) << 5))) = f2bf(acc[mi][oj][r]);
            }
    __syncthreads();
    {
        int og = t >> 4, rr = t & 15;
        uint16_t* zb = ztb + ((size_t)(b * 16 + og) * S_ + s0) * 16;
        #pragma unroll
        for (int k = 0; k < 4; k++) {
            int s = rr * 4 + k;
            u32x4 v0 = *(u32x4*)(tz + s * 512 + ((og * 32) ^ ((s & 7) << 5)));
            u32x4 v1 = *(u32x4*)(tz + s * 512 + (((og * 32) ^ ((s & 7) << 5)) | 16));
            __builtin_nontemporal_store(v0, (u32x4*)(zb + (size_t)s * 16));
            __builtin_nontemporal_store(v1, (u32x4*)(zb + (size_t)s * 16 + 8));
        }
    }
}

// ---------------- K2b: y1 = W1@p1, o-blocked bf16 ----------------
__global__ void __launch_bounds__(256, 4)
k2b(const float* __restrict__ p1, const uint16_t* __restrict__ w1b,
    uint16_t* __restrict__ y1) {
    int i = blockIdx.x;            // 2048
    int b = i >> 7, n0 = (i & 127) * 32;
    int t = threadIdx.x, l = t & 63, w = t >> 6;
    int oW = w * 64;
    __shared__ uint16_t pt[32 * 64];   // [n][c], 128B rows, swz <<4
    {
        int nn = t & 31;
        const float* p1b = p1 + (size_t)b * D1_ * N_ + n0;
        #pragma unroll
        for (int j = 0; j < 4; j++) {
            int cp = (t >> 5) + 8 * j;
            float lo = p1b[(size_t)(2 * cp) * N_ + nn];
            float hi = p1b[(size_t)(2 * cp + 1) * N_ + nn];
            uint32_t pk = (uint32_t)f2bf(lo) | ((uint32_t)f2bf(hi) << 16);
            *(uint32_t*)((char*)pt + nn * 128 + ((cp * 4) ^ ((nn & 7) << 4))) = pk;
        }
    }
    bf16x8 af[2][4];
    #pragma unroll
    for (int ks = 0; ks < 2; ks++)
        #pragma unroll
        for (int mi = 0; mi < 4; mi++) {
            int o = oW + mi * 16 + (l & 15);
            af[ks][mi] = *(const bf16x8*)(w1b + (size_t)o * 64 + ks * 32 + (l >> 4) * 8);
        }
    f32x4 acc[4][2] = {};   // [mi(o)][bj(n)]
    __syncthreads();
    #pragma unroll
    for (int ks = 0; ks < 2; ks++) {
        bf16x8 bf[2];
        int co = ks * 32 + (l >> 4) * 8;
        #pragma unroll
        for (int bj = 0; bj < 2; bj++) {
            int nn = bj * 16 + (l & 15);
            bf[bj] = *(const bf16x8*)((const char*)pt + nn * 128 + ((co * 2) ^ ((nn & 7) << 4)));
        }
        #pragma unroll
        for (int mi = 0; mi < 4; mi++)
            #pragma unroll
            for (int bj = 0; bj < 2; bj++)
                acc[mi][bj] = __builtin_amdgcn_mfma_f32_16x16x32_bf16(
                    af[ks][mi], bf[bj], acc[mi][bj], 0, 0, 0);
    }
    #pragma unroll
    for (int mi = 0; mi < 4; mi++) {
        int og = w * 4 + mi;
        uint16_t* yb = y1 + ((size_t)(b * 16 + og)) * N_ * 16;
        #pragma unroll
        for (int bj = 0; bj < 2; bj++) {
            int n = n0 + bj * 16 + (l & 15);
            int oo = (l >> 4) * 4;
            u32x2 v;
            v.x = (uint32_t)f2bf(acc[mi][bj][0]) | ((uint32_t)f2bf(acc[mi][bj][1]) << 16);
            v.y = (uint32_t)f2bf(acc[mi][bj][2]) | ((uint32_t)f2bf(acc[mi][bj][3]) << 16);
            __builtin_nontemporal_store(v, (u32x2*)(yb + (size_t)n * 16 + oo));
        }
    }
}

// ---------------- K3a: LDS-staged gather -> y2 bf16 + BN partials ----------------
// 1024 threads (16 waves), grid 512 -> 2 blocks/CU, 32 waves/CU (full occupancy)
__global__ void __launch_bounds__(1024, 8)
k3a(const uint16_t* __restrict__ y1, const uint16_t* __restrict__ ztb,
    const int* __restrict__ idxw, uint16_t* __restrict__ y2,
    float* __restrict__ partials) {
    __shared__ char zsm[49152];          // [1024 s][48B] rows (32B used)
    __shared__ float red[16][16][2];
    int bi = blockIdx.x;                 // 512: b*32 + og*2 + nh
    int b = bi >> 5, og = (bi >> 1) & 15, nh = bi & 1;
    int u = threadIdx.x, l = u & 63, w = u >> 6;   // 16 waves
    {
        const u32x4* src = (const u32x4*)(ztb + ((size_t)(b * 16 + og)) * S_ * 16);
        #pragma unroll
        for (int k = 0; k < 2; k++) {
            int g = k * 1024 + u;
            u32x4 v = src[g];
            *(u32x4*)(zsm + (g >> 1) * 48 + (g & 1) * 16) = v;
        }
    }
    __syncthreads();
    int q = l >> 2, sub = l & 3;
    float s1l[4] = {0.f, 0.f, 0.f, 0.f}, s2l[4] = {0.f, 0.f, 0.f, 0.f};
    int nbase = nh * 2048 + w * 128;
    const uint16_t* y1b = y1 + ((size_t)(b * 16 + og)) * N_ * 16;
    uint16_t* y2b = y2 + ((size_t)(b * 16 + og)) * N_ * 16;
    #pragma unroll 2
    for (int it = 0; it < 8; it++) {
        int n = nbase + it * 16 + q;
        u32x2 y1v = __builtin_nontemporal_load((const u32x2*)(y1b + (size_t)n * 16 + sub * 4));
        const int* ib = idxw + ((size_t)(b * N_ + n)) * 8;
        int4   iv = *(const int4*)ib;
        float4 wv = *((const float4*)ib + 1);
        u32x2 z0 = *(const u32x2*)(zsm + iv.x * 48 + sub * 8);
        u32x2 z1 = *(const u32x2*)(zsm + iv.y * 48 + sub * 8);
        u32x2 z2 = *(const u32x2*)(zsm + iv.z * 48 + sub * 8);
        float a0 = bf2f(y1v.x & 0xffff) + wv.x * bf2f(z0.x & 0xffff) + wv.y * bf2f(z1.x & 0xffff) + wv.z * bf2f(z2.x & 0xffff);
        float a1 = bf2f(y1v.x >> 16)    + wv.x * bf2f(z0.x >> 16)    + wv.y * bf2f(z1.x >> 16)    + wv.z * bf2f(z2.x >> 16);
        float a2 = bf2f(y1v.y & 0xffff) + wv.x * bf2f(z0.y & 0xffff) + wv.y * bf2f(z1.y & 0xffff) + wv.z * bf2f(z2.y & 0xffff);
        float a3 = bf2f(y1v.y >> 16)    + wv.x * bf2f(z0.y >> 16)    + wv.y * bf2f(z1.y >> 16)    + wv.z * bf2f(z2.y >> 16);
        s1l[0] += a0; s2l[0] += a0 * a0;
        s1l[1] += a1; s2l[1] += a1 * a1;
        s1l[2] += a2; s2l[2] += a2 * a2;
        s1l[3] += a3; s2l[3] += a3 * a3;
        u32x2 vv;
        vv.x = (uint32_t)f2bf(a0) | ((uint32_t)f2bf(a1) << 16);
        vv.y = (uint32_t)f2bf(a2) | ((uint32_t)f2bf(a3) << 16);
        __builtin_nontemporal_store(vv, (u32x2*)(y2b + (size_t)n * 16 + sub * 4));
    }
    #pragma unroll
    for (int m = 4; m <= 32; m <<= 1)
        #pragma unroll
        for (int j = 0; j < 4; j++) {
            s1l[j] += __shfl_xor(s1l[j], m);
            s2l[j] += __shfl_xor(s2l[j], m);
        }
    if (l < 4) {
        #pragma unroll
        for (int j = 0; j < 4; j++) {
            red[w][sub * 4 + j][0] = s1l[j];
            red[w][sub * 4 + j][1] = s2l[j];
        }
    }
    __syncthreads();
    if (u < 32) {
        int oi = u >> 1, st = u & 1;
        float s = 0.f;
        #pragma unroll
        for (int ww = 0; ww < 16; ww++) s += red[ww][oi][st];
        partials[(size_t)bi * 32 + oi * 2 + st] = s;
    }
}

// ---------------- K3c: stats + y2 -> LDS transpose -> BN+ReLU -> out ----------------
__global__ void __launch_bounds__(256, 8)
k3c(const uint16_t* __restrict__ y2, const float* __restrict__ partials,
    const float* __restrict__ gamma, const float* __restrict__ beta,
    float* __restrict__ out) {
    __shared__ uint16_t ty[16 * 256];   // [16 o][256 n] bf16, byte XOR bit4-6 by (o&7)
    __shared__ float stat[32];
    __shared__ float sbsh[32];
    int bi = blockIdx.x;                // 4096: b*256 + og*16 + nc
    int b = bi >> 8, og = (bi >> 4) & 15, nc = bi & 15;
    int u = threadIdx.x;
    // issue streaming loads first
    const uint16_t* src = y2 + (((size_t)(b * 16 + og)) * N_ + nc * 256) * 16;
    u32x4 va = __builtin_nontemporal_load((const u32x4*)(src + (size_t)u * 16));
    u32x4 vb = __builtin_nontemporal_load((const u32x4*)(src + (size_t)u * 16 + 8));
    // per-block BN stats for this og (partials are L2-hot, 4KB)
    if (u < 32) {
        int oi = u >> 1, st = u & 1;
        float s = 0.f;
        #pragma unroll 4
        for (int t2 = 0; t2 < 32; t2++) {
            int row = (t2 >> 1) * 32 + og * 2 + (t2 & 1);
            s += partials[(size_t)row * 32 + oi * 2 + st];
        }
        stat[u] = s;
    }
    __syncthreads();
    if (u < 16) {
        float mean = stat[u * 2] / 65536.0f;
        float var  = stat[u * 2 + 1] / 65536.0f - mean * mean;
        int o_g = og * 16 + u;
        float scale = gamma[o_g] * rsqrtf(var + 1e-5f);
        sbsh[u * 2]     = scale;
        sbsh[u * 2 + 1] = beta[o_g] - mean * scale;
    }
    uint32_t words[8] = {va.x, va.y, va.z, va.w, vb.x, vb.y, vb.z, vb.w};
    #pragma unroll
    for (int h = 0; h < 8; h++) {
        int o0 = h * 2, o1 = h * 2 + 1;
        *(uint16_t*)((char*)ty + o0 * 512 + ((u * 2) ^ ((o0 & 7) << 4))) = (uint16_t)(words[h] & 0xffff);
        *(uint16_t*)((char*)ty + o1 * 512 + ((u * 2) ^ ((o1 & 7) << 4))) = (uint16_t)(words[h] >> 16);
    }
    __syncthreads();
    int o = u >> 4, k = u & 15;
    int x = (o & 7) << 4;
    int o_g = og * 16 + o;
    float scale = sbsh[o * 2], bias = sbsh[o * 2 + 1];
    float* dst = out + ((size_t)(b * OC_ + o_g)) * N_ + nc * 256;
    #pragma unroll
    for (int g2 = 0; g2 < 4; g2++) {
        uint64_t z = *(const uint64_t*)((const char*)ty + o * 512 + ((g2 * 128 + k * 8) ^ x));
        f32x4 r;
        r.x = fmaxf(0.f, fmaf(bf2f((uint32_t)(z       ) & 0xffff), scale, bias));
        r.y = fmaxf(0.f, fmaf(bf2f((uint32_t)(z >> 16 ) & 0xffff), scale, bias));
        r.z = fmaxf(0.f, fmaf(bf2f((uint32_t)(z >> 32 ) & 0xffff), scale, bias));
        r.w = fmaxf(0.f, fmaf(bf2f((uint32_t)(z >> 48 ) & 0xffff), scale, bias));
        __builtin_nontemporal_store(r, (f32x4*)(dst + g2 * 64 + k * 4));
    }
}

extern "C" void kernel_launch(void* const* d_in, const int* in_sizes, int n_in,
                              void* d_out, int out_size, void* d_ws, size_t ws_size,
                              hipStream_t stream) {
    const float* xyz1  = (const float*)d_in[0];
    const float* xyz2  = (const float*)d_in[1];
    const float* p1    = (const float*)d_in[2];
    const float* p2    = (const float*)d_in[3];
    const float* W     = (const float*)d_in[4];
    const float* gamma = (const float*)d_in[5];
    const float* beta  = (const float*)d_in[6];
    float* out = (float*)d_out;
    char* ws = (char*)d_ws;
    if (ws_size < (size_t)WS_NEED) return;

    int*      idxw     = (int*)(ws + IDXW_OFF);
    uint16_t* ztb      = (uint16_t*)(ws + ZTB_OFF);
    uint16_t* y1       = (uint16_t*)(ws + Y1_OFF);
    uint16_t* y2       = (uint16_t*)(ws + Y2_OFF);
    float*    partials = (float*)(ws + PART_OFF);
    uint16_t* w1b      = (uint16_t*)(ws + W1B_OFF);
    uint16_t* w2b      = (uint16_t*)(ws + W2B_OFF);

    hipLaunchKernelGGL(k0_prep,    dim3(320),     dim3(256),  0, stream, W, w1b, w2b);
    hipLaunchKernelGGL(k1_threenn, dim3(128, 16), dim3(256),  0, stream, xyz1, xyz2, idxw);
    hipLaunchKernelGGL(k2_z,       dim3(16, 16),  dim3(256),  0, stream, p2, w2b, ztb);
    hipLaunchKernelGGL(k2b,        dim3(2048),    dim3(256),  0, stream, p1, w1b, y1);
    hipLaunchKernelGGL(k3a,        dim3(512),     dim3(1024), 0, stream, y1, ztb, idxw, y2, partials);
    hipLaunchKernelGGL(k3c,        dim3(4096),    dim3(256),  0, stream, y2, partials, gamma, beta, out);
}

// Round 11
// 109.709 us; speedup vs baseline: 1.9961x; 1.1120x over previous
//
#include <hip/hip_runtime.h>
#include <stdint.h>

// PointNet Feature Propagation, MI355X.
//  K01: fused  k1 three_nn (blocks 0..2047)  +  k0 weight-convert (blocks 2048..2367)
//  K2f: fused  k2_z = W2@p2 (blocks 0..255)  +  k2b y1 = W1@p1 (blocks 256..2303)
//  K3a: y2 = y1 + sum_k w_k * ztb[idx_k]  (LDS-staged gather) + BN partials
//  K3c: y2 -> LDS transpose -> (stats from partials) BN+ReLU -> d_out f32

#define B_   16
#define N_   4096
#define S_   1024
#define D1_  64
#define D2_  256
#define OC_  256

typedef __attribute__((ext_vector_type(8))) short bf16x8;
typedef __attribute__((ext_vector_type(4))) float f32x4;
typedef __attribute__((ext_vector_type(4))) unsigned int u32x4;
typedef __attribute__((ext_vector_type(2))) unsigned int u32x2;

// workspace layout (bytes)
#define IDXW_OFF 0u           // 2 MB
#define ZTB_OFF  2097152u     // 8 MB
#define Y1_OFF   10485760u    // 32 MB
#define Y2_OFF   44040192u    // 32 MB
#define PART_OFF 77594624u    // 64 KB
#define W1B_OFF  77662208u    // 32 KB
#define W2B_OFF  77694976u    // 128 KB
#define WS_NEED  77826048u

__device__ __forceinline__ uint16_t f2bf(float f) {
    union { float f; uint32_t u; } v; v.f = f;
    uint32_t r = v.u + 0x7FFFu + ((v.u >> 16) & 1u);   // RNE
    return (uint16_t)(r >> 16);
}
__device__ __forceinline__ float bf2f(uint32_t h) {
    union { uint32_t u; float f; } v; v.u = h << 16;
    return v.f;
}

#define INSERT(d, sidx, d0, d1, d2, i0, i1, i2) do {                      \
    bool ca = (d) < (d2); bool cb = (d) < (d1); bool cc = (d) < (d0);     \
    float _n1 = __builtin_amdgcn_fmed3f((d), (d0), (d1));                 \
    float _n2 = __builtin_amdgcn_fmed3f((d), (d1), (d2));                 \
    int _j2 = cb ? (i1) : (ca ? (sidx) : (i2));                           \
    int _j1 = cc ? (i0) : (cb ? (sidx) : (i1));                           \
    i0 = cc ? (sidx) : (i0);                                              \
    d0 = fminf((d), (d0)); d1 = _n1; d2 = _n2; i1 = _j1; i2 = _j2;        \
} while (0)

// ---------------- K01: three_nn (0..2047) + weight convert (2048..2367) ----------------
__global__ void __launch_bounds__(256, 8)
k01(const float* __restrict__ xyz1, const float* __restrict__ xyz2,
    int* __restrict__ idxw, const float* __restrict__ W,
    uint16_t* __restrict__ w1b, uint16_t* __restrict__ w2b) {
    __shared__ float4 pts[8 * 129];
    int i = blockIdx.x;
    int t = threadIdx.x;
    if (i >= 2048) {
        int e = (i - 2048) * 256 + t;
        if (e < OC_ * 320) {
            int o = e / 320, c = e % 320;
            uint16_t b = f2bf(W[e]);
            if (c < 64) w1b[o * 64 + c] = b;
            else        w2b[o * 256 + (c - 64)] = b;
        }
        return;
    }
    int b  = i >> 7;
    int n0 = (i & 127) * 32;

    for (int s = t; s < S_; s += 256) {
        const float* p = xyz2 + ((size_t)b * S_ + s) * 3;
        pts[(s >> 7) * 129 + (s & 127)] = make_float4(p[0], p[1], p[2], 0.f);
    }
    __syncthreads();

    int chunk = t & 7, nidx = t >> 3;   // 32 n-slots x 8 chunks
    int n = n0 + nidx;
    const float* q = xyz1 + ((size_t)b * N_ + n) * 3;
    float ax = q[0], ay = q[1], az = q[2];

    float d0 = 3.4e38f, d1 = 3.4e38f, d2 = 3.4e38f;
    int   i0 = 0, i1 = 0, i2 = 0;

    const float4* base = pts + chunk * 129;
    int sbase = chunk * 128;
    #pragma unroll 4
    for (int j = 0; j < 128; j++) {
        float4 qq = base[j];
        int s = sbase + j;
        float dx = ax - qq.x, dy = ay - qq.y, dz = az - qq.z;
        float d = fmaf(dz, dz, fmaf(dy, dy, dx * dx));
        INSERT(d, s, d0, d1, d2, i0, i1, i2);
    }
    #pragma unroll
    for (int m = 1; m <= 4; m <<= 1) {
        float e0 = __shfl_xor(d0, m), e1 = __shfl_xor(d1, m), e2 = __shfl_xor(d2, m);
        int   g0 = __shfl_xor(i0, m), g1 = __shfl_xor(i1, m), g2 = __shfl_xor(i2, m);
        INSERT(e0, g0, d0, d1, d2, i0, i1, i2);
        INSERT(e1, g1, d0, d1, d2, i0, i1, i2);
        INSERT(e2, g2, d0, d1, d2, i0, i1, i2);
    }
    if (chunk == 0) {
        float r0 = 1.0f / (d0 + 1e-8f), r1 = 1.0f / (d1 + 1e-8f), r2 = 1.0f / (d2 + 1e-8f);
        float rs = r0 + r1 + r2;
        float* fw = (float*)idxw;
        int bb = (b * N_ + n) * 8;
        idxw[bb + 0] = i0; idxw[bb + 1] = i1; idxw[bb + 2] = i2;
        fw[bb + 4] = r0 / rs; fw[bb + 5] = r1 / rs; fw[bb + 6] = r2 / rs;
    }
}

// ---------------- K2f: k2_z (0..255) + k2b (256..2303) ----------------
__global__ void __launch_bounds__(256, 4)
k2f(const float* __restrict__ p2, const uint16_t* __restrict__ w2b,
    uint16_t* __restrict__ ztb, const float* __restrict__ p1,
    const uint16_t* __restrict__ w1b, uint16_t* __restrict__ y1) {
    __shared__ char smem[40960];
    int i = blockIdx.x;
    int t = threadIdx.x, l = t & 63, w = t >> 6;
    if (i < 256) {
        // ---- k2_z: ztb = W2@p2, o-blocked bf16 ----
        uint16_t* a_t = (uint16_t*)smem;            // [64 s][64 c], 128B rows, swz <<4
        uint16_t* w_t = (uint16_t*)(smem + 8192);   // [256 o][64 c]
        int b = i >> 4, s0 = (i & 15) * 64;

        f32x4 acc[4][4] = {};   // [mi(s)][oj(o)]
        for (int ck = 0; ck < 4; ck++) {
            __syncthreads();
            {
                int sA = w * 16 + (l & 15);
                const float* p2b = p2 + ((size_t)b * D2_ + (size_t)ck * 64) * S_ + s0;
                #pragma unroll
                for (int j = 0; j < 8; j++) {
                    int cp = (l >> 4) + 4 * j;
                    float lo = p2b[(size_t)(2 * cp) * S_ + sA];
                    float hi = p2b[(size_t)(2 * cp + 1) * S_ + sA];
                    uint32_t pk = (uint32_t)f2bf(lo) | ((uint32_t)f2bf(hi) << 16);
                    *(uint32_t*)((char*)a_t + sA * 128 + ((cp * 4) ^ ((sA & 7) << 4))) = pk;
                }
            }
            {
                int wp = t & 31, orow0 = t >> 5;
                #pragma unroll 4
                for (int jj = 0; jj < 32; jj++) {
                    int o = orow0 + 8 * jj;
                    uint32_t v = *(const uint32_t*)(w2b + (size_t)o * 256 + ck * 64 + 2 * wp);
                    *(uint32_t*)((char*)w_t + o * 128 + ((wp * 4) ^ ((o & 7) << 4))) = v;
                }
            }
            __syncthreads();
            #pragma unroll
            for (int ks = 0; ks < 2; ks++) {
                bf16x8 a[4], bb[4];
                int co = ks * 32 + (l >> 4) * 8;
                #pragma unroll
                for (int mi = 0; mi < 4; mi++) {
                    int s = mi * 16 + (l & 15);
                    a[mi] = *(const bf16x8*)((const char*)a_t + s * 128 + ((co * 2) ^ ((s & 7) << 4)));
                }
                #pragma unroll
                for (int oj = 0; oj < 4; oj++) {
                    int o = w * 64 + oj * 16 + (l & 15);
                    bb[oj] = *(const bf16x8*)((const char*)w_t + o * 128 + ((co * 2) ^ ((o & 7) << 4)));
                }
                #pragma unroll
                for (int mi = 0; mi < 4; mi++)
                    #pragma unroll
                    for (int oj = 0; oj < 4; oj++)
                        acc[mi][oj] = __builtin_amdgcn_mfma_f32_16x16x32_bf16(
                            a[mi], bb[oj], acc[mi][oj], 0, 0, 0);
            }
        }
        __syncthreads();
        char* tz = smem;   // [64 s][512 B], swz <<5
        #pragma unroll
        for (int mi = 0; mi < 4; mi++)
            #pragma unroll
            for (int oj = 0; oj < 4; oj++)
                #pragma unroll
                for (int r = 0; r < 4; r++) {
                    int sl = mi * 16 + (l >> 4) * 4 + r;
                    int o  = w * 64 + oj * 16 + (l & 15);
                    *(uint16_t*)(tz + sl * 512 + ((o * 2) ^ ((sl & 7) << 5))) = f2bf(acc[mi][oj][r]);
                }
        __syncthreads();
        {
            int og = t >> 4, rr = t & 15;
            uint16_t* zb = ztb + ((size_t)(b * 16 + og) * S_ + s0) * 16;
            #pragma unroll
            for (int k = 0; k < 4; k++) {
                int s = rr * 4 + k;
                u32x4 v0 = *(u32x4*)(tz + s * 512 + ((og * 32) ^ ((s & 7) << 5)));
                u32x4 v1 = *(u32x4*)(tz + s * 512 + (((og * 32) ^ ((s & 7) << 5)) | 16));
                __builtin_nontemporal_store(v0, (u32x4*)(zb + (size_t)s * 16));
                __builtin_nontemporal_store(v1, (u32x4*)(zb + (size_t)s * 16 + 8));
            }
        }
    } else {
        // ---- k2b: y1 = W1@p1, o-blocked bf16 ----
        int j2 = i - 256;
        int b = j2 >> 7, n0 = (j2 & 127) * 32;
        int oW = w * 64;
        uint16_t* pt = (uint16_t*)smem;   // [32 n][64 c], 128B rows, swz <<4
        {
            int nn = t & 31;
            const float* p1b = p1 + (size_t)b * D1_ * N_ + n0;
            #pragma unroll
            for (int j = 0; j < 4; j++) {
                int cp = (t >> 5) + 8 * j;
                float lo = p1b[(size_t)(2 * cp) * N_ + nn];
                float hi = p1b[(size_t)(2 * cp + 1) * N_ + nn];
                uint32_t pk = (uint32_t)f2bf(lo) | ((uint32_t)f2bf(hi) << 16);
                *(uint32_t*)((char*)pt + nn * 128 + ((cp * 4) ^ ((nn & 7) << 4))) = pk;
            }
        }
        bf16x8 af[2][4];
        #pragma unroll
        for (int ks = 0; ks < 2; ks++)
            #pragma unroll
            for (int mi = 0; mi < 4; mi++) {
                int o = oW + mi * 16 + (l & 15);
                af[ks][mi] = *(const bf16x8*)(w1b + (size_t)o * 64 + ks * 32 + (l >> 4) * 8);
            }
        f32x4 acc[4][2] = {};   // [mi(o)][bj(n)]
        __syncthreads();
        #pragma unroll
        for (int ks = 0; ks < 2; ks++) {
            bf16x8 bf[2];
            int co = ks * 32 + (l >> 4) * 8;
            #pragma unroll
            for (int bj = 0; bj < 2; bj++) {
                int nn = bj * 16 + (l & 15);
                bf[bj] = *(const bf16x8*)((const char*)pt + nn * 128 + ((co * 2) ^ ((nn & 7) << 4)));
            }
            #pragma unroll
            for (int mi = 0; mi < 4; mi++)
                #pragma unroll
                for (int bj = 0; bj < 2; bj++)
                    acc[mi][bj] = __builtin_amdgcn_mfma_f32_16x16x32_bf16(
                        af[ks][mi], bf[bj], acc[mi][bj], 0, 0, 0);
        }
        #pragma unroll
        for (int mi = 0; mi < 4; mi++) {
            int og = w * 4 + mi;
            uint16_t* yb = y1 + ((size_t)(b * 16 + og)) * N_ * 16;
            #pragma unroll
            for (int bj = 0; bj < 2; bj++) {
                int n = n0 + bj * 16 + (l & 15);
                int oo = (l >> 4) * 4;
                u32x2 v;
                v.x = (uint32_t)f2bf(acc[mi][bj][0]) | ((uint32_t)f2bf(acc[mi][bj][1]) << 16);
                v.y = (uint32_t)f2bf(acc[mi][bj][2]) | ((uint32_t)f2bf(acc[mi][bj][3]) << 16);
                __builtin_nontemporal_store(v, (u32x2*)(yb + (size_t)n * 16 + oo));
            }
        }
    }
}

// ---------------- K3a: LDS-staged gather -> y2 bf16 + BN partials ----------------
__global__ void __launch_bounds__(1024, 8)
k3a(const uint16_t* __restrict__ y1, const uint16_t* __restrict__ ztb,
    const int* __restrict__ idxw, uint16_t* __restrict__ y2,
    float* __restrict__ partials) {
    __shared__ char zsm[49152];          // [1024 s][48B] rows (32B used)
    __shared__ float red[16][16][2];
    int bi = blockIdx.x;                 // 512: b*32 + og*2 + nh
    int b = bi >> 5, og = (bi >> 1) & 15, nh = bi & 1;
    int u = threadIdx.x, l = u & 63, w = u >> 6;   // 16 waves
    {
        const u32x4* src = (const u32x4*)(ztb + ((size_t)(b * 16 + og)) * S_ * 16);
        #pragma unroll
        for (int k = 0; k < 2; k++) {
            int g = k * 1024 + u;
            u32x4 v = src[g];
            *(u32x4*)(zsm + (g >> 1) * 48 + (g & 1) * 16) = v;
        }
    }
    __syncthreads();
    int q = l >> 2, sub = l & 3;
    float s1l[4] = {0.f, 0.f, 0.f, 0.f}, s2l[4] = {0.f, 0.f, 0.f, 0.f};
    int nbase = nh * 2048 + w * 128;
    const uint16_t* y1b = y1 + ((size_t)(b * 16 + og)) * N_ * 16;
    uint16_t* y2b = y2 + ((size_t)(b * 16 + og)) * N_ * 16;
    #pragma unroll 2
    for (int it = 0; it < 8; it++) {
        int n = nbase + it * 16 + q;
        u32x2 y1v = __builtin_nontemporal_load((const u32x2*)(y1b + (size_t)n * 16 + sub * 4));
        const int* ib = idxw + ((size_t)(b * N_ + n)) * 8;
        int4   iv = *(const int4*)ib;
        float4 wv = *((const float4*)ib + 1);
        u32x2 z0 = *(const u32x2*)(zsm + iv.x * 48 + sub * 8);
        u32x2 z1 = *(const u32x2*)(zsm + iv.y * 48 + sub * 8);
        u32x2 z2 = *(const u32x2*)(zsm + iv.z * 48 + sub * 8);
        float a0 = bf2f(y1v.x & 0xffff) + wv.x * bf2f(z0.x & 0xffff) + wv.y * bf2f(z1.x & 0xffff) + wv.z * bf2f(z2.x & 0xffff);
        float a1 = bf2f(y1v.x >> 16)    + wv.x * bf2f(z0.x >> 16)    + wv.y * bf2f(z1.x >> 16)    + wv.z * bf2f(z2.x >> 16);
        float a2 = bf2f(y1v.y & 0xffff) + wv.x * bf2f(z0.y & 0xffff) + wv.y * bf2f(z1.y & 0xffff) + wv.z * bf2f(z2.y & 0xffff);
        float a3 = bf2f(y1v.y >> 16)    + wv.x * bf2f(z0.y >> 16)    + wv.y * bf2f(z1.y >> 16)    + wv.z * bf2f(z2.y >> 16);
        s1l[0] += a0; s2l[0] += a0 * a0;
        s1l[1] += a1; s2l[1] += a1 * a1;
        s1l[2] += a2; s2l[2] += a2 * a2;
        s1l[3] += a3; s2l[3] += a3 * a3;
        u32x2 vv;
        vv.x = (uint32_t)f2bf(a0) | ((uint32_t)f2bf(a1) << 16);
        vv.y = (uint32_t)f2bf(a2) | ((uint32_t)f2bf(a3) << 16);
        __builtin_nontemporal_store(vv, (u32x2*)(y2b + (size_t)n * 16 + sub * 4));
    }
    #pragma unroll
    for (int m = 4; m <= 32; m <<= 1)
        #pragma unroll
        for (int j = 0; j < 4; j++) {
            s1l[j] += __shfl_xor(s1l[j], m);
            s2l[j] += __shfl_xor(s2l[j], m);
        }
    if (l < 4) {
        #pragma unroll
        for (int j = 0; j < 4; j++) {
            red[w][sub * 4 + j][0] = s1l[j];
            red[w][sub * 4 + j][1] = s2l[j];
        }
    }
    __syncthreads();
    if (u < 32) {
        int oi = u >> 1, st = u & 1;
        float s = 0.f;
        #pragma unroll
        for (int ww = 0; ww < 16; ww++) s += red[ww][oi][st];
        partials[(size_t)bi * 32 + oi * 2 + st] = s;
    }
}

// ---------------- K3c: stats + y2 -> LDS transpose -> BN+ReLU -> out ----------------
__global__ void __launch_bounds__(256, 8)
k3c(const uint16_t* __restrict__ y2, const float* __restrict__ partials,
    const float* __restrict__ gamma, const float* __restrict__ beta,
    float* __restrict__ out) {
    __shared__ uint16_t ty[16 * 256];   // [16 o][256 n] bf16, byte XOR bit4 by (o&7)
    __shared__ float stat[32];
    __shared__ float sbsh[32];
    int bi = blockIdx.x;                // 4096: b*256 + og*16 + nc
    int b = bi >> 8, og = (bi >> 4) & 15, nc = bi & 15;
    int u = threadIdx.x;
    const uint16_t* src = y2 + (((size_t)(b * 16 + og)) * N_ + nc * 256) * 16;
    u32x4 va = __builtin_nontemporal_load((const u32x4*)(src + (size_t)u * 16));
    u32x4 vb = __builtin_nontemporal_load((const u32x4*)(src + (size_t)u * 16 + 8));
    if (u < 32) {
        int oi = u >> 1, st = u & 1;
        float s = 0.f;
        #pragma unroll 4
        for (int t2 = 0; t2 < 32; t2++) {
            int row = (t2 >> 1) * 32 + og * 2 + (t2 & 1);
            s += partials[(size_t)row * 32 + oi * 2 + st];
        }
        stat[u] = s;
    }
    __syncthreads();
    if (u < 16) {
        float mean = stat[u * 2] / 65536.0f;
        float var  = stat[u * 2 + 1] / 65536.0f - mean * mean;
        int o_g = og * 16 + u;
        float scale = gamma[o_g] * rsqrtf(var + 1e-5f);
        sbsh[u * 2]     = scale;
        sbsh[u * 2 + 1] = beta[o_g] - mean * scale;
    }
    uint32_t words[8] = {va.x, va.y, va.z, va.w, vb.x, vb.y, vb.z, vb.w};
    #pragma unroll
    for (int h = 0; h < 8; h++) {
        int o0 = h * 2, o1 = h * 2 + 1;
        *(uint16_t*)((char*)ty + o0 * 512 + ((u * 2) ^ ((o0 & 7) << 4))) = (uint16_t)(words[h] & 0xffff);
        *(uint16_t*)((char*)ty + o1 * 512 + ((u * 2) ^ ((o1 & 7) << 4))) = (uint16_t)(words[h] >> 16);
    }
    __syncthreads();
    int o = u >> 4, k = u & 15;
    int x = (o & 7) << 4;
    int o_g = og * 16 + o;
    float scale = sbsh[o * 2], bias = sbsh[o * 2 + 1];
    float* dst = out + ((size_t)(b * OC_ + o_g)) * N_ + nc * 256;
    #pragma unroll
    for (int g2 = 0; g2 < 4; g2++) {
        uint64_t z = *(const uint64_t*)((const char*)ty + o * 512 + ((g2 * 128 + k * 8) ^ x));
        f32x4 r;
        r.x = fmaxf(0.f, fmaf(bf2f((uint32_t)(z       ) & 0xffff), scale, bias));
        r.y = fmaxf(0.f, fmaf(bf2f((uint32_t)(z >> 16 ) & 0xffff), scale, bias));
        r.z = fmaxf(0.f, fmaf(bf2f((uint32_t)(z >> 32 ) & 0xffff), scale, bias));
        r.w = fmaxf(0.f, fmaf(bf2f((uint32_t)(z >> 48 ) & 0xffff), scale, bias));
        __builtin_nontemporal_store(r, (f32x4*)(dst + g2 * 64 + k * 4));
    }
}

extern "C" void kernel_launch(void* const* d_in, const int* in_sizes, int n_in,
                              void* d_out, int out_size, void* d_ws, size_t ws_size,
                              hipStream_t stream) {
    const float* xyz1  = (const float*)d_in[0];
    const float* xyz2  = (const float*)d_in[1];
    const float* p1    = (const float*)d_in[2];
    const float* p2    = (const float*)d_in[3];
    const float* W     = (const float*)d_in[4];
    const float* gamma = (const float*)d_in[5];
    const float* beta  = (const float*)d_in[6];
    float* out = (float*)d_out;
    char* ws = (char*)d_ws;
    if (ws_size < (size_t)WS_NEED) return;

    int*      idxw     = (int*)(ws + IDXW_OFF);
    uint16_t* ztb      = (uint16_t*)(ws + ZTB_OFF);
    uint16_t* y1       = (uint16_t*)(ws + Y1_OFF);
    uint16_t* y2       = (uint16_t*)(ws + Y2_OFF);
    float*    partials = (float*)(ws + PART_OFF);
    uint16_t* w1b      = (uint16_t*)(ws + W1B_OFF);
    uint16_t* w2b      = (uint16_t*)(ws + W2B_OFF);

    hipLaunchKernelGGL(k01, dim3(2368), dim3(256),  0, stream,
                       xyz1, xyz2, idxw, W, w1b, w2b);
    hipLaunchKernelGGL(k2f, dim3(2304), dim3(256),  0, stream,
                       p2, w2b, ztb, p1, w1b, y1);
    hipLaunchKernelGGL(k3a, dim3(512),  dim3(1024), 0, stream,
                       y1, ztb, idxw, y2, partials);
    hipLaunchKernelGGL(k3c, dim3(4096), dim3(256),  0, stream,
                       y2, partials, gamma, beta, out);
}

// Round 12
// 100.507 us; speedup vs baseline: 2.1788x; 1.0916x over previous
//
#include <hip/hip_runtime.h>
#include <stdint.h>

// PointNet Feature Propagation, MI355X.
//  K01: fused  k1 three_nn (blocks 0..2047)  +  k0 weight-convert (blocks 2048..2367)
//  K2f: fused  k2_z = W2@p2 (blocks 0..511, 32s-tile, W2 direct from L2, 1 sync)
//             + k2b y1 = W1@p1 (blocks 512..2559)
//  K3a: y2 = y1 + sum_k w_k * ztb[idx_k]  (LDS-staged gather) + BN partials
//  K3c: y2 -> LDS transpose -> (stats from partials) BN+ReLU -> d_out f32

#define B_   16
#define N_   4096
#define S_   1024
#define D1_  64
#define D2_  256
#define OC_  256

typedef __attribute__((ext_vector_type(8))) short bf16x8;
typedef __attribute__((ext_vector_type(4))) float f32x4;
typedef __attribute__((ext_vector_type(4))) unsigned int u32x4;
typedef __attribute__((ext_vector_type(2))) unsigned int u32x2;

// workspace layout (bytes)
#define IDXW_OFF 0u           // 2 MB
#define ZTB_OFF  2097152u     // 8 MB
#define Y1_OFF   10485760u    // 32 MB
#define Y2_OFF   44040192u    // 32 MB
#define PART_OFF 77594624u    // 64 KB
#define W1B_OFF  77662208u    // 32 KB
#define W2B_OFF  77694976u    // 128 KB
#define WS_NEED  77826048u

__device__ __forceinline__ uint16_t f2bf(float f) {
    union { float f; uint32_t u; } v; v.f = f;
    uint32_t r = v.u + 0x7FFFu + ((v.u >> 16) & 1u);   // RNE
    return (uint16_t)(r >> 16);
}
__device__ __forceinline__ float bf2f(uint32_t h) {
    union { uint32_t u; float f; } v; v.u = h << 16;
    return v.f;
}

#define INSERT(d, sidx, d0, d1, d2, i0, i1, i2) do {                      \
    bool ca = (d) < (d2); bool cb = (d) < (d1); bool cc = (d) < (d0);     \
    float _n1 = __builtin_amdgcn_fmed3f((d), (d0), (d1));                 \
    float _n2 = __builtin_amdgcn_fmed3f((d), (d1), (d2));                 \
    int _j2 = cb ? (i1) : (ca ? (sidx) : (i2));                           \
    int _j1 = cc ? (i0) : (cb ? (sidx) : (i1));                           \
    i0 = cc ? (sidx) : (i0);                                              \
    d0 = fminf((d), (d0)); d1 = _n1; d2 = _n2; i1 = _j1; i2 = _j2;        \
} while (0)

// ---------------- K01: three_nn (0..2047) + weight convert (2048..2367) ----------------
__global__ void __launch_bounds__(256, 8)
k01(const float* __restrict__ xyz1, const float* __restrict__ xyz2,
    int* __restrict__ idxw, const float* __restrict__ W,
    uint16_t* __restrict__ w1b, uint16_t* __restrict__ w2b) {
    __shared__ float4 pts[8 * 129];
    int i = blockIdx.x;
    int t = threadIdx.x;
    if (i >= 2048) {
        int e = (i - 2048) * 256 + t;
        if (e < OC_ * 320) {
            int o = e / 320, c = e % 320;
            uint16_t b = f2bf(W[e]);
            if (c < 64) w1b[o * 64 + c] = b;
            else        w2b[o * 256 + (c - 64)] = b;
        }
        return;
    }
    int b  = i >> 7;
    int n0 = (i & 127) * 32;

    for (int s = t; s < S_; s += 256) {
        const float* p = xyz2 + ((size_t)b * S_ + s) * 3;
        pts[(s >> 7) * 129 + (s & 127)] = make_float4(p[0], p[1], p[2], 0.f);
    }
    __syncthreads();

    int chunk = t & 7, nidx = t >> 3;   // 32 n-slots x 8 chunks
    int n = n0 + nidx;
    const float* q = xyz1 + ((size_t)b * N_ + n) * 3;
    float ax = q[0], ay = q[1], az = q[2];

    float d0 = 3.4e38f, d1 = 3.4e38f, d2 = 3.4e38f;
    int   i0 = 0, i1 = 0, i2 = 0;

    const float4* base = pts + chunk * 129;
    int sbase = chunk * 128;
    #pragma unroll 4
    for (int j = 0; j < 128; j++) {
        float4 qq = base[j];
        int s = sbase + j;
        float dx = ax - qq.x, dy = ay - qq.y, dz = az - qq.z;
        float d = fmaf(dz, dz, fmaf(dy, dy, dx * dx));
        INSERT(d, s, d0, d1, d2, i0, i1, i2);
    }
    #pragma unroll
    for (int m = 1; m <= 4; m <<= 1) {
        float e0 = __shfl_xor(d0, m), e1 = __shfl_xor(d1, m), e2 = __shfl_xor(d2, m);
        int   g0 = __shfl_xor(i0, m), g1 = __shfl_xor(i1, m), g2 = __shfl_xor(i2, m);
        INSERT(e0, g0, d0, d1, d2, i0, i1, i2);
        INSERT(e1, g1, d0, d1, d2, i0, i1, i2);
        INSERT(e2, g2, d0, d1, d2, i0, i1, i2);
    }
    if (chunk == 0) {
        float r0 = 1.0f / (d0 + 1e-8f), r1 = 1.0f / (d1 + 1e-8f), r2 = 1.0f / (d2 + 1e-8f);
        float rs = r0 + r1 + r2;
        float* fw = (float*)idxw;
        int bb = (b * N_ + n) * 8;
        idxw[bb + 0] = i0; idxw[bb + 1] = i1; idxw[bb + 2] = i2;
        fw[bb + 4] = r0 / rs; fw[bb + 5] = r1 / rs; fw[bb + 6] = r2 / rs;
    }
}

// ---------------- K2f: k2_z (0..511) + k2b (512..2559) ----------------
__global__ void __launch_bounds__(256, 8)
k2f(const float* __restrict__ p2, const uint16_t* __restrict__ w2b,
    uint16_t* __restrict__ ztb, const float* __restrict__ p1,
    const uint16_t* __restrict__ w1b, uint16_t* __restrict__ y1) {
    __shared__ char smem[16384];
    int i = blockIdx.x;
    int t = threadIdx.x, l = t & 63, w = t >> 6;
    if (i < 512) {
        // ---- k2_z: ztb = W2@p2; A staged in LDS (full K), W2 direct from L2 ----
        uint16_t* a_t = (uint16_t*)smem;   // [32 s][256 c] bf16, 512B rows, swz <<4
        int b = i >> 5, s0 = (i & 31) * 32;
        int sA = t & 31, cpg = t >> 5;
        const float* p2b = p2 + (size_t)b * D2_ * S_ + s0;
        #pragma unroll
        for (int j = 0; j < 16; j++) {
            int cp = cpg + 8 * j;
            float lo = p2b[(size_t)(2 * cp) * S_ + sA];
            float hi = p2b[(size_t)(2 * cp + 1) * S_ + sA];
            uint32_t pk = (uint32_t)f2bf(lo) | ((uint32_t)f2bf(hi) << 16);
            *(uint32_t*)((char*)a_t + sA * 512 + ((cp * 4) ^ ((sA & 7) << 4))) = pk;
        }
        __syncthreads();
        f32x4 acc[2][4] = {};   // [mi(s16)][oj(o16)]
        int ls = l & 15, swzs = (ls & 7) << 4;
        #pragma unroll
        for (int ks = 0; ks < 8; ks++) {
            int co = ks * 32 + (l >> 4) * 8;
            bf16x8 a0 = *(const bf16x8*)((const char*)a_t + ls * 512 + ((co * 2) ^ swzs));
            bf16x8 a1 = *(const bf16x8*)((const char*)a_t + (16 + ls) * 512 + ((co * 2) ^ swzs));
            bf16x8 bbf[4];
            #pragma unroll
            for (int oj = 0; oj < 4; oj++) {
                int o = w * 64 + oj * 16 + ls;
                bbf[oj] = *(const bf16x8*)(w2b + (size_t)o * 256 + co);
            }
            #pragma unroll
            for (int oj = 0; oj < 4; oj++) {
                acc[0][oj] = __builtin_amdgcn_mfma_f32_16x16x32_bf16(a0, bbf[oj], acc[0][oj], 0, 0, 0);
                acc[1][oj] = __builtin_amdgcn_mfma_f32_16x16x32_bf16(a1, bbf[oj], acc[1][oj], 0, 0, 0);
            }
        }
        // direct fragment-native store: 16 lanes cover one 32B [s][16o] row
        #pragma unroll
        for (int mi = 0; mi < 2; mi++)
            #pragma unroll
            for (int oj = 0; oj < 4; oj++) {
                int og = w * 4 + oj;
                uint16_t* zb = ztb + ((size_t)(b * 16 + og) * S_ + s0 + mi * 16 + (l >> 4) * 4) * 16 + ls;
                #pragma unroll
                for (int r = 0; r < 4; r++)
                    zb[(size_t)r * 16] = f2bf(acc[mi][oj][r]);
            }
    } else {
        // ---- k2b: y1 = W1@p1, o-blocked bf16 ----
        int j2 = i - 512;
        int b = j2 >> 7, n0 = (j2 & 127) * 32;
        int oW = w * 64;
        uint16_t* pt = (uint16_t*)smem;   // [32 n][64 c], 128B rows, swz <<4
        {
            int nn = t & 31;
            const float* p1b = p1 + (size_t)b * D1_ * N_ + n0;
            #pragma unroll
            for (int j = 0; j < 4; j++) {
                int cp = (t >> 5) + 8 * j;
                float lo = p1b[(size_t)(2 * cp) * N_ + nn];
                float hi = p1b[(size_t)(2 * cp + 1) * N_ + nn];
                uint32_t pk = (uint32_t)f2bf(lo) | ((uint32_t)f2bf(hi) << 16);
                *(uint32_t*)((char*)pt + nn * 128 + ((cp * 4) ^ ((nn & 7) << 4))) = pk;
            }
        }
        bf16x8 af[2][4];
        #pragma unroll
        for (int ks = 0; ks < 2; ks++)
            #pragma unroll
            for (int mi = 0; mi < 4; mi++) {
                int o = oW + mi * 16 + (l & 15);
                af[ks][mi] = *(const bf16x8*)(w1b + (size_t)o * 64 + ks * 32 + (l >> 4) * 8);
            }
        f32x4 acc[4][2] = {};   // [mi(o)][bj(n)]
        __syncthreads();
        #pragma unroll
        for (int ks = 0; ks < 2; ks++) {
            bf16x8 bf[2];
            int co = ks * 32 + (l >> 4) * 8;
            #pragma unroll
            for (int bj = 0; bj < 2; bj++) {
                int nn = bj * 16 + (l & 15);
                bf[bj] = *(const bf16x8*)((const char*)pt + nn * 128 + ((co * 2) ^ ((nn & 7) << 4)));
            }
            #pragma unroll
            for (int mi = 0; mi < 4; mi++)
                #pragma unroll
                for (int bj = 0; bj < 2; bj++)
                    acc[mi][bj] = __builtin_amdgcn_mfma_f32_16x16x32_bf16(
                        af[ks][mi], bf[bj], acc[mi][bj], 0, 0, 0);
        }
        #pragma unroll
        for (int mi = 0; mi < 4; mi++) {
            int og = w * 4 + mi;
            uint16_t* yb = y1 + ((size_t)(b * 16 + og)) * N_ * 16;
            #pragma unroll
            for (int bj = 0; bj < 2; bj++) {
                int n = n0 + bj * 16 + (l & 15);
                int oo = (l >> 4) * 4;
                u32x2 v;
                v.x = (uint32_t)f2bf(acc[mi][bj][0]) | ((uint32_t)f2bf(acc[mi][bj][1]) << 16);
                v.y = (uint32_t)f2bf(acc[mi][bj][2]) | ((uint32_t)f2bf(acc[mi][bj][3]) << 16);
                __builtin_nontemporal_store(v, (u32x2*)(yb + (size_t)n * 16 + oo));
            }
        }
    }
}

// ---------------- K3a: LDS-staged gather -> y2 bf16 + BN partials ----------------
__global__ void __launch_bounds__(1024, 8)
k3a(const uint16_t* __restrict__ y1, const uint16_t* __restrict__ ztb,
    const int* __restrict__ idxw, uint16_t* __restrict__ y2,
    float* __restrict__ partials) {
    __shared__ char zsm[49152];          // [1024 s][48B] rows (32B used)
    __shared__ float red[16][16][2];
    int bi = blockIdx.x;                 // 512: b*32 + og*2 + nh
    int b = bi >> 5, og = (bi >> 1) & 15, nh = bi & 1;
    int u = threadIdx.x, l = u & 63, w = u >> 6;   // 16 waves
    {
        const u32x4* src = (const u32x4*)(ztb + ((size_t)(b * 16 + og)) * S_ * 16);
        #pragma unroll
        for (int k = 0; k < 2; k++) {
            int g = k * 1024 + u;
            u32x4 v = src[g];
            *(u32x4*)(zsm + (g >> 1) * 48 + (g & 1) * 16) = v;
        }
    }
    __syncthreads();
    int q = l >> 2, sub = l & 3;
    float s1l[4] = {0.f, 0.f, 0.f, 0.f}, s2l[4] = {0.f, 0.f, 0.f, 0.f};
    int nbase = nh * 2048 + w * 128;
    const uint16_t* y1b = y1 + ((size_t)(b * 16 + og)) * N_ * 16;
    uint16_t* y2b = y2 + ((size_t)(b * 16 + og)) * N_ * 16;
    #pragma unroll 2
    for (int it = 0; it < 8; it++) {
        int n = nbase + it * 16 + q;
        u32x2 y1v = __builtin_nontemporal_load((const u32x2*)(y1b + (size_t)n * 16 + sub * 4));
        const int* ib = idxw + ((size_t)(b * N_ + n)) * 8;
        int4   iv = *(const int4*)ib;
        float4 wv = *((const float4*)ib + 1);
        u32x2 z0 = *(const u32x2*)(zsm + iv.x * 48 + sub * 8);
        u32x2 z1 = *(const u32x2*)(zsm + iv.y * 48 + sub * 8);
        u32x2 z2 = *(const u32x2*)(zsm + iv.z * 48 + sub * 8);
        float a0 = bf2f(y1v.x & 0xffff) + wv.x * bf2f(z0.x & 0xffff) + wv.y * bf2f(z1.x & 0xffff) + wv.z * bf2f(z2.x & 0xffff);
        float a1 = bf2f(y1v.x >> 16)    + wv.x * bf2f(z0.x >> 16)    + wv.y * bf2f(z1.x >> 16)    + wv.z * bf2f(z2.x >> 16);
        float a2 = bf2f(y1v.y & 0xffff) + wv.x * bf2f(z0.y & 0xffff) + wv.y * bf2f(z1.y & 0xffff) + wv.z * bf2f(z2.y & 0xffff);
        float a3 = bf2f(y1v.y >> 16)    + wv.x * bf2f(z0.y >> 16)    + wv.y * bf2f(z1.y >> 16)    + wv.z * bf2f(z2.y >> 16);
        s1l[0] += a0; s2l[0] += a0 * a0;
        s1l[1] += a1; s2l[1] += a1 * a1;
        s1l[2] += a2; s2l[2] += a2 * a2;
        s1l[3] += a3; s2l[3] += a3 * a3;
        u32x2 vv;
        vv.x = (uint32_t)f2bf(a0) | ((uint32_t)f2bf(a1) << 16);
        vv.y = (uint32_t)f2bf(a2) | ((uint32_t)f2bf(a3) << 16);
        __builtin_nontemporal_store(vv, (u32x2*)(y2b + (size_t)n * 16 + sub * 4));
    }
    #pragma unroll
    for (int m = 4; m <= 32; m <<= 1)
        #pragma unroll
        for (int j = 0; j < 4; j++) {
            s1l[j] += __shfl_xor(s1l[j], m);
            s2l[j] += __shfl_xor(s2l[j], m);
        }
    if (l < 4) {
        #pragma unroll
        for (int j = 0; j < 4; j++) {
            red[w][sub * 4 + j][0] = s1l[j];
            red[w][sub * 4 + j][1] = s2l[j];
        }
    }
    __syncthreads();
    if (u < 32) {
        int oi = u >> 1, st = u & 1;
        float s = 0.f;
        #pragma unroll
        for (int ww = 0; ww < 16; ww++) s += red[ww][oi][st];
        partials[(size_t)bi * 32 + oi * 2 + st] = s;
    }
}

// ---------------- K3c: stats + y2 -> LDS transpose -> BN+ReLU -> out ----------------
__global__ void __launch_bounds__(256, 8)
k3c(const uint16_t* __restrict__ y2, const float* __restrict__ partials,
    const float* __restrict__ gamma, const float* __restrict__ beta,
    float* __restrict__ out) {
    __shared__ uint16_t ty[16 * 256];   // [16 o][256 n] bf16, byte XOR bit4 by (o&7)
    __shared__ float stat[32];
    __shared__ float sbsh[32];
    int bi = blockIdx.x;                // 4096: b*256 + og*16 + nc
    int b = bi >> 8, og = (bi >> 4) & 15, nc = bi & 15;
    int u = threadIdx.x;
    const uint16_t* src = y2 + (((size_t)(b * 16 + og)) * N_ + nc * 256) * 16;
    u32x4 va = __builtin_nontemporal_load((const u32x4*)(src + (size_t)u * 16));
    u32x4 vb = __builtin_nontemporal_load((const u32x4*)(src + (size_t)u * 16 + 8));
    if (u < 32) {
        int oi = u >> 1, st = u & 1;
        float s = 0.f;
        #pragma unroll 4
        for (int t2 = 0; t2 < 32; t2++) {
            int row = (t2 >> 1) * 32 + og * 2 + (t2 & 1);
            s += partials[(size_t)row * 32 + oi * 2 + st];
        }
        stat[u] = s;
    }
    __syncthreads();
    if (u < 16) {
        float mean = stat[u * 2] / 65536.0f;
        float var  = stat[u * 2 + 1] / 65536.0f - mean * mean;
        int o_g = og * 16 + u;
        float scale = gamma[o_g] * rsqrtf(var + 1e-5f);
        sbsh[u * 2]     = scale;
        sbsh[u * 2 + 1] = beta[o_g] - mean * scale;
    }
    uint32_t words[8] = {va.x, va.y, va.z, va.w, vb.x, vb.y, vb.z, vb.w};
    #pragma unroll
    for (int h = 0; h < 8; h++) {
        int o0 = h * 2, o1 = h * 2 + 1;
        *(uint16_t*)((char*)ty + o0 * 512 + ((u * 2) ^ ((o0 & 7) << 4))) = (uint16_t)(words[h] & 0xffff);
        *(uint16_t*)((char*)ty + o1 * 512 + ((u * 2) ^ ((o1 & 7) << 4))) = (uint16_t)(words[h] >> 16);
    }
    __syncthreads();
    int o = u >> 4, k = u & 15;
    int x = (o & 7) << 4;
    int o_g = og * 16 + o;
    float scale = sbsh[o * 2], bias = sbsh[o * 2 + 1];
    float* dst = out + ((size_t)(b * OC_ + o_g)) * N_ + nc * 256;
    #pragma unroll
    for (int g2 = 0; g2 < 4; g2++) {
        uint64_t z = *(const uint64_t*)((const char*)ty + o * 512 + ((g2 * 128 + k * 8) ^ x));
        f32x4 r;
        r.x = fmaxf(0.f, fmaf(bf2f((uint32_t)(z       ) & 0xffff), scale, bias));
        r.y = fmaxf(0.f, fmaf(bf2f((uint32_t)(z >> 16 ) & 0xffff), scale, bias));
        r.z = fmaxf(0.f, fmaf(bf2f((uint32_t)(z >> 32 ) & 0xffff), scale, bias));
        r.w = fmaxf(0.f, fmaf(bf2f((uint32_t)(z >> 48 ) & 0xffff), scale, bias));
        __builtin_nontemporal_store(r, (f32x4*)(dst + g2 * 64 + k * 4));
    }
}

extern "C" void kernel_launch(void* const* d_in, const int* in_sizes, int n_in,
                              void* d_out, int out_size, void* d_ws, size_t ws_size,
                              hipStream_t stream) {
    const float* xyz1  = (const float*)d_in[0];
    const float* xyz2  = (const float*)d_in[1];
    const float* p1    = (const float*)d_in[2];
    const float* p2    = (const float*)d_in[3];
    const float* W     = (const float*)d_in[4];
    const float* gamma = (const float*)d_in[5];
    const float* beta  = (const float*)d_in[6];
    float* out = (float*)d_out;
    char* ws = (char*)d_ws;
    if (ws_size < (size_t)WS_NEED) return;

    int*      idxw     = (int*)(ws + IDXW_OFF);
    uint16_t* ztb      = (uint16_t*)(ws + ZTB_OFF);
    uint16_t* y1       = (uint16_t*)(ws + Y1_OFF);
    uint16_t* y2       = (uint16_t*)(ws + Y2_OFF);
    float*    partials = (float*)(ws + PART_OFF);
    uint16_t* w1b      = (uint16_t*)(ws + W1B_OFF);
    uint16_t* w2b      = (uint16_t*)(ws + W2B_OFF);

    hipLaunchKernelGGL(k01, dim3(2368), dim3(256),  0, stream,
                       xyz1, xyz2, idxw, W, w1b, w2b);
    hipLaunchKernelGGL(k2f, dim3(2560), dim3(256),  0, stream,
                       p2, w2b, ztb, p1, w1b, y1);
    hipLaunchKernelGGL(k3a, dim3(512),  dim3(1024), 0, stream,
                       y1, ztb, idxw, y2, partials);
    hipLaunchKernelGGL(k3c, dim3(4096), dim3(256),  0, stream,
                       y2, partials, gamma, beta, out);
}

// Round 13
// 97.041 us; speedup vs baseline: 2.2567x; 1.0357x over previous
//
#include <hip/hip_runtime.h>
#include <stdint.h>

// PointNet Feature Propagation, MI355X.  3 launches:
//  A  : fused  k2_z = W2@p2 (blocks 0..511)  +  k1 three_nn (512..2559)
//             + k2b y1 = W1@p1 (2560..4607).  W read f32-direct (inline bf16 cvt).
//  K3a: y2 = y1 + sum_k w_k * ztb[idx_k]  (LDS-staged gather) + BN partials
//  K3c: y2 -> LDS transpose -> (stats from partials) BN+ReLU -> d_out f32

#define B_   16
#define N_   4096
#define S_   1024
#define D1_  64
#define D2_  256
#define OC_  256

typedef __attribute__((ext_vector_type(8))) short bf16x8;
typedef __attribute__((ext_vector_type(4))) float f32x4;
typedef __attribute__((ext_vector_type(4))) unsigned int u32x4;
typedef __attribute__((ext_vector_type(2))) unsigned int u32x2;

// workspace layout (bytes)
#define IDXW_OFF 0u           // 2 MB
#define ZTB_OFF  2097152u     // 8 MB
#define Y1_OFF   10485760u    // 32 MB
#define Y2_OFF   44040192u    // 32 MB
#define PART_OFF 77594624u    // 64 KB
#define WS_NEED  77826048u

__device__ __forceinline__ uint16_t f2bf(float f) {
    union { float f; uint32_t u; } v; v.f = f;
    uint32_t r = v.u + 0x7FFFu + ((v.u >> 16) & 1u);   // RNE
    return (uint16_t)(r >> 16);
}
__device__ __forceinline__ float bf2f(uint32_t h) {
    union { uint32_t u; float f; } v; v.u = h << 16;
    return v.f;
}
// 8 consecutive f32 -> bf16x8 (32B-aligned source)
__device__ __forceinline__ bf16x8 cvt8(const float* p) {
    f32x4 a = *(const f32x4*)p;
    f32x4 b = *(const f32x4*)(p + 4);
    union { uint32_t u[4]; bf16x8 v; } r;
    r.u[0] = (uint32_t)f2bf(a.x) | ((uint32_t)f2bf(a.y) << 16);
    r.u[1] = (uint32_t)f2bf(a.z) | ((uint32_t)f2bf(a.w) << 16);
    r.u[2] = (uint32_t)f2bf(b.x) | ((uint32_t)f2bf(b.y) << 16);
    r.u[3] = (uint32_t)f2bf(b.z) | ((uint32_t)f2bf(b.w) << 16);
    return r.v;
}

#define INSERT(d, sidx, d0, d1, d2, i0, i1, i2) do {                      \
    bool ca = (d) < (d2); bool cb = (d) < (d1); bool cc = (d) < (d0);     \
    float _n1 = __builtin_amdgcn_fmed3f((d), (d0), (d1));                 \
    float _n2 = __builtin_amdgcn_fmed3f((d), (d1), (d2));                 \
    int _j2 = cb ? (i1) : (ca ? (sidx) : (i2));                           \
    int _j1 = cc ? (i0) : (cb ? (sidx) : (i1));                           \
    i0 = cc ? (sidx) : (i0);                                              \
    d0 = fminf((d), (d0)); d1 = _n1; d2 = _n2; i1 = _j1; i2 = _j2;        \
} while (0)

// ---------------- A: k2_z (0..511) + k1 (512..2559) + k2b (2560..4607) ----------------
__global__ void __launch_bounds__(256, 8)
kA(const float* __restrict__ xyz1, const float* __restrict__ xyz2,
   int* __restrict__ idxw, const float* __restrict__ W,
   const float* __restrict__ p1, const float* __restrict__ p2,
   uint16_t* __restrict__ ztb, uint16_t* __restrict__ y1) {
    __shared__ char smem[16512];
    int i = blockIdx.x;
    int t = threadIdx.x, l = t & 63, w = t >> 6;
    if (i < 512) {
        // ---- k2_z: ztb = W2@p2; A staged in LDS (full K), W2 f32-direct from L2 ----
        uint16_t* a_t = (uint16_t*)smem;   // [32 s][256 c] bf16, 512B rows, swz <<4
        int b = i >> 5, s0 = (i & 31) * 32;
        int sA = t & 31, cpg = t >> 5;
        const float* p2b = p2 + (size_t)b * D2_ * S_ + s0;
        #pragma unroll
        for (int j = 0; j < 16; j++) {
            int cp = cpg + 8 * j;
            float lo = p2b[(size_t)(2 * cp) * S_ + sA];
            float hi = p2b[(size_t)(2 * cp + 1) * S_ + sA];
            uint32_t pk = (uint32_t)f2bf(lo) | ((uint32_t)f2bf(hi) << 16);
            *(uint32_t*)((char*)a_t + sA * 512 + ((cp * 4) ^ ((sA & 7) << 4))) = pk;
        }
        __syncthreads();
        f32x4 acc[2][4] = {};   // [mi(s16)][oj(o16)]
        int ls = l & 15, swzs = (ls & 7) << 4;
        #pragma unroll
        for (int ks = 0; ks < 8; ks++) {
            int co = ks * 32 + (l >> 4) * 8;
            bf16x8 a0 = *(const bf16x8*)((const char*)a_t + ls * 512 + ((co * 2) ^ swzs));
            bf16x8 a1 = *(const bf16x8*)((const char*)a_t + (16 + ls) * 512 + ((co * 2) ^ swzs));
            bf16x8 bbf[4];
            #pragma unroll
            for (int oj = 0; oj < 4; oj++) {
                int o = w * 64 + oj * 16 + ls;
                bbf[oj] = cvt8(W + (size_t)o * 320 + 64 + co);
            }
            #pragma unroll
            for (int oj = 0; oj < 4; oj++) {
                acc[0][oj] = __builtin_amdgcn_mfma_f32_16x16x32_bf16(a0, bbf[oj], acc[0][oj], 0, 0, 0);
                acc[1][oj] = __builtin_amdgcn_mfma_f32_16x16x32_bf16(a1, bbf[oj], acc[1][oj], 0, 0, 0);
            }
        }
        // direct fragment-native store: 16 lanes cover one 32B [s][16o] row
        #pragma unroll
        for (int mi = 0; mi < 2; mi++)
            #pragma unroll
            for (int oj = 0; oj < 4; oj++) {
                int og = w * 4 + oj;
                uint16_t* zb = ztb + ((size_t)(b * 16 + og) * S_ + s0 + mi * 16 + (l >> 4) * 4) * 16 + ls;
                #pragma unroll
                for (int r = 0; r < 4; r++)
                    zb[(size_t)r * 16] = f2bf(acc[mi][oj][r]);
            }
    } else if (i < 2560) {
        // ---- k1: three_nn ----
        int j1 = i - 512;
        int b  = j1 >> 7;
        int n0 = (j1 & 127) * 32;
        float4* pts = (float4*)smem;    // [8 chunks][129]

        for (int s = t; s < S_; s += 256) {
            const float* p = xyz2 + ((size_t)b * S_ + s) * 3;
            pts[(s >> 7) * 129 + (s & 127)] = make_float4(p[0], p[1], p[2], 0.f);
        }
        __syncthreads();

        int chunk = t & 7, nidx = t >> 3;
        int n = n0 + nidx;
        const float* q = xyz1 + ((size_t)b * N_ + n) * 3;
        float ax = q[0], ay = q[1], az = q[2];

        float d0 = 3.4e38f, d1 = 3.4e38f, d2 = 3.4e38f;
        int   i0 = 0, i1 = 0, i2 = 0;

        const float4* base = pts + chunk * 129;
        int sbase = chunk * 128;
        #pragma unroll 4
        for (int j = 0; j < 128; j++) {
            float4 qq = base[j];
            int s = sbase + j;
            float dx = ax - qq.x, dy = ay - qq.y, dz = az - qq.z;
            float d = fmaf(dz, dz, fmaf(dy, dy, dx * dx));
            INSERT(d, s, d0, d1, d2, i0, i1, i2);
        }
        #pragma unroll
        for (int m = 1; m <= 4; m <<= 1) {
            float e0 = __shfl_xor(d0, m), e1 = __shfl_xor(d1, m), e2 = __shfl_xor(d2, m);
            int   g0 = __shfl_xor(i0, m), g1 = __shfl_xor(i1, m), g2 = __shfl_xor(i2, m);
            INSERT(e0, g0, d0, d1, d2, i0, i1, i2);
            INSERT(e1, g1, d0, d1, d2, i0, i1, i2);
            INSERT(e2, g2, d0, d1, d2, i0, i1, i2);
        }
        if (chunk == 0) {
            float r0 = 1.0f / (d0 + 1e-8f), r1 = 1.0f / (d1 + 1e-8f), r2 = 1.0f / (d2 + 1e-8f);
            float rs = r0 + r1 + r2;
            float* fw = (float*)idxw;
            int bb = (b * N_ + n) * 8;
            idxw[bb + 0] = i0; idxw[bb + 1] = i1; idxw[bb + 2] = i2;
            fw[bb + 4] = r0 / rs; fw[bb + 5] = r1 / rs; fw[bb + 6] = r2 / rs;
        }
    } else {
        // ---- k2b: y1 = W1@p1, W1 f32-direct ----
        int j2 = i - 2560;
        int b = j2 >> 7, n0 = (j2 & 127) * 32;
        int oW = w * 64;
        uint16_t* pt = (uint16_t*)smem;   // [32 n][64 c], 128B rows, swz <<4
        {
            int nn = t & 31;
            const float* p1b = p1 + (size_t)b * D1_ * N_ + n0;
            #pragma unroll
            for (int j = 0; j < 4; j++) {
                int cp = (t >> 5) + 8 * j;
                float lo = p1b[(size_t)(2 * cp) * N_ + nn];
                float hi = p1b[(size_t)(2 * cp + 1) * N_ + nn];
                uint32_t pk = (uint32_t)f2bf(lo) | ((uint32_t)f2bf(hi) << 16);
                *(uint32_t*)((char*)pt + nn * 128 + ((cp * 4) ^ ((nn & 7) << 4))) = pk;
            }
        }
        bf16x8 af[2][4];
        #pragma unroll
        for (int ks = 0; ks < 2; ks++)
            #pragma unroll
            for (int mi = 0; mi < 4; mi++) {
                int o = oW + mi * 16 + (l & 15);
                af[ks][mi] = cvt8(W + (size_t)o * 320 + ks * 32 + (l >> 4) * 8);
            }
        f32x4 acc[4][2] = {};   // [mi(o)][bj(n)]
        __syncthreads();
        #pragma unroll
        for (int ks = 0; ks < 2; ks++) {
            bf16x8 bf[2];
            int co = ks * 32 + (l >> 4) * 8;
            #pragma unroll
            for (int bj = 0; bj < 2; bj++) {
                int nn = bj * 16 + (l & 15);
                bf[bj] = *(const bf16x8*)((const char*)pt + nn * 128 + ((co * 2) ^ ((nn & 7) << 4)));
            }
            #pragma unroll
            for (int mi = 0; mi < 4; mi++)
                #pragma unroll
                for (int bj = 0; bj < 2; bj++)
                    acc[mi][bj] = __builtin_amdgcn_mfma_f32_16x16x32_bf16(
                        af[ks][mi], bf[bj], acc[mi][bj], 0, 0, 0);
        }
        #pragma unroll
        for (int mi = 0; mi < 4; mi++) {
            int og = w * 4 + mi;
            uint16_t* yb = y1 + ((size_t)(b * 16 + og)) * N_ * 16;
            #pragma unroll
            for (int bj = 0; bj < 2; bj++) {
                int n = n0 + bj * 16 + (l & 15);
                int oo = (l >> 4) * 4;
                u32x2 v;
                v.x = (uint32_t)f2bf(acc[mi][bj][0]) | ((uint32_t)f2bf(acc[mi][bj][1]) << 16);
                v.y = (uint32_t)f2bf(acc[mi][bj][2]) | ((uint32_t)f2bf(acc[mi][bj][3]) << 16);
                __builtin_nontemporal_store(v, (u32x2*)(yb + (size_t)n * 16 + oo));
            }
        }
    }
}

// ---------------- K3a: LDS-staged gather -> y2 bf16 + BN partials ----------------
__global__ void __launch_bounds__(1024, 8)
k3a(const uint16_t* __restrict__ y1, const uint16_t* __restrict__ ztb,
    const int* __restrict__ idxw, uint16_t* __restrict__ y2,
    float* __restrict__ partials) {
    __shared__ char zsm[49152];          // [1024 s][48B] rows (32B used)
    __shared__ float red[16][16][2];
    int bi = blockIdx.x;                 // 512: b*32 + og*2 + nh
    int b = bi >> 5, og = (bi >> 1) & 15, nh = bi & 1;
    int u = threadIdx.x, l = u & 63, w = u >> 6;   // 16 waves
    {
        const u32x4* src = (const u32x4*)(ztb + ((size_t)(b * 16 + og)) * S_ * 16);
        #pragma unroll
        for (int k = 0; k < 2; k++) {
            int g = k * 1024 + u;
            u32x4 v = src[g];
            *(u32x4*)(zsm + (g >> 1) * 48 + (g & 1) * 16) = v;
        }
    }
    __syncthreads();
    int q = l >> 2, sub = l & 3;
    float s1l[4] = {0.f, 0.f, 0.f, 0.f}, s2l[4] = {0.f, 0.f, 0.f, 0.f};
    int nbase = nh * 2048 + w * 128;
    const uint16_t* y1b = y1 + ((size_t)(b * 16 + og)) * N_ * 16;
    uint16_t* y2b = y2 + ((size_t)(b * 16 + og)) * N_ * 16;
    #pragma unroll 2
    for (int it = 0; it < 8; it++) {
        int n = nbase + it * 16 + q;
        u32x2 y1v = __builtin_nontemporal_load((const u32x2*)(y1b + (size_t)n * 16 + sub * 4));
        const int* ib = idxw + ((size_t)(b * N_ + n)) * 8;
        int4   iv = *(const int4*)ib;
        float4 wv = *((const float4*)ib + 1);
        u32x2 z0 = *(const u32x2*)(zsm + iv.x * 48 + sub * 8);
        u32x2 z1 = *(const u32x2*)(zsm + iv.y * 48 + sub * 8);
        u32x2 z2 = *(const u32x2*)(zsm + iv.z * 48 + sub * 8);
        float a0 = bf2f(y1v.x & 0xffff) + wv.x * bf2f(z0.x & 0xffff) + wv.y * bf2f(z1.x & 0xffff) + wv.z * bf2f(z2.x & 0xffff);
        float a1 = bf2f(y1v.x >> 16)    + wv.x * bf2f(z0.x >> 16)    + wv.y * bf2f(z1.x >> 16)    + wv.z * bf2f(z2.x >> 16);
        float a2 = bf2f(y1v.y & 0xffff) + wv.x * bf2f(z0.y & 0xffff) + wv.y * bf2f(z1.y & 0xffff) + wv.z * bf2f(z2.y & 0xffff);
        float a3 = bf2f(y1v.y >> 16)    + wv.x * bf2f(z0.y >> 16)    + wv.y * bf2f(z1.y >> 16)    + wv.z * bf2f(z2.y >> 16);
        s1l[0] += a0; s2l[0] += a0 * a0;
        s1l[1] += a1; s2l[1] += a1 * a1;
        s1l[2] += a2; s2l[2] += a2 * a2;
        s1l[3] += a3; s2l[3] += a3 * a3;
        u32x2 vv;
        vv.x = (uint32_t)f2bf(a0) | ((uint32_t)f2bf(a1) << 16);
        vv.y = (uint32_t)f2bf(a2) | ((uint32_t)f2bf(a3) << 16);
        __builtin_nontemporal_store(vv, (u32x2*)(y2b + (size_t)n * 16 + sub * 4));
    }
    #pragma unroll
    for (int m = 4; m <= 32; m <<= 1)
        #pragma unroll
        for (int j = 0; j < 4; j++) {
            s1l[j] += __shfl_xor(s1l[j], m);
            s2l[j] += __shfl_xor(s2l[j], m);
        }
    if (l < 4) {
        #pragma unroll
        for (int j = 0; j < 4; j++) {
            red[w][sub * 4 + j][0] = s1l[j];
            red[w][sub * 4 + j][1] = s2l[j];
        }
    }
    __syncthreads();
    if (u < 32) {
        int oi = u >> 1, st = u & 1;
        float s = 0.f;
        #pragma unroll
        for (int ww = 0; ww < 16; ww++) s += red[ww][oi][st];
        partials[(size_t)bi * 32 + oi * 2 + st] = s;
    }
}

// ---------------- K3c: stats + y2 -> LDS transpose -> BN+ReLU -> out ----------------
__global__ void __launch_bounds__(256, 8)
k3c(const uint16_t* __restrict__ y2, const float* __restrict__ partials,
    const float* __restrict__ gamma, const float* __restrict__ beta,
    float* __restrict__ out) {
    __shared__ uint16_t ty[16 * 256];   // [16 o][256 n] bf16, byte XOR bit4 by (o&7)
    __shared__ float stat[32];
    __shared__ float sbsh[32];
    int bi = blockIdx.x;                // 4096: b*256 + og*16 + nc
    int b = bi >> 8, og = (bi >> 4) & 15, nc = bi & 15;
    int u = threadIdx.x;
    const uint16_t* src = y2 + (((size_t)(b * 16 + og)) * N_ + nc * 256) * 16;
    u32x4 va = __builtin_nontemporal_load((const u32x4*)(src + (size_t)u * 16));
    u32x4 vb = __builtin_nontemporal_load((const u32x4*)(src + (size_t)u * 16 + 8));
    if (u < 32) {
        int oi = u >> 1, st = u & 1;
        float s = 0.f;
        #pragma unroll 4
        for (int t2 = 0; t2 < 32; t2++) {
            int row = (t2 >> 1) * 32 + og * 2 + (t2 & 1);
            s += partials[(size_t)row * 32 + oi * 2 + st];
        }
        stat[u] = s;
    }
    __syncthreads();
    if (u < 16) {
        float mean = stat[u * 2] / 65536.0f;
        float var  = stat[u * 2 + 1] / 65536.0f - mean * mean;
        int o_g = og * 16 + u;
        float scale = gamma[o_g] * rsqrtf(var + 1e-5f);
        sbsh[u * 2]     = scale;
        sbsh[u * 2 + 1] = beta[o_g] - mean * scale;
    }
    uint32_t words[8] = {va.x, va.y, va.z, va.w, vb.x, vb.y, vb.z, vb.w};
    #pragma unroll
    for (int h = 0; h < 8; h++) {
        int o0 = h * 2, o1 = h * 2 + 1;
        *(uint16_t*)((char*)ty + o0 * 512 + ((u * 2) ^ ((o0 & 7) << 4))) = (uint16_t)(words[h] & 0xffff);
        *(uint16_t*)((char*)ty + o1 * 512 + ((u * 2) ^ ((o1 & 7) << 4))) = (uint16_t)(words[h] >> 16);
    }
    __syncthreads();
    int o = u >> 4, k = u & 15;
    int x = (o & 7) << 4;
    int o_g = og * 16 + o;
    float scale = sbsh[o * 2], bias = sbsh[o * 2 + 1];
    float* dst = out + ((size_t)(b * OC_ + o_g)) * N_ + nc * 256;
    #pragma unroll
    for (int g2 = 0; g2 < 4; g2++) {
        uint64_t z = *(const uint64_t*)((const char*)ty + o * 512 + ((g2 * 128 + k * 8) ^ x));
        f32x4 r;
        r.x = fmaxf(0.f, fmaf(bf2f((uint32_t)(z       ) & 0xffff), scale, bias));
        r.y = fmaxf(0.f, fmaf(bf2f((uint32_t)(z >> 16 ) & 0xffff), scale, bias));
        r.z = fmaxf(0.f, fmaf(bf2f((uint32_t)(z >> 32 ) & 0xffff), scale, bias));
        r.w = fmaxf(0.f, fmaf(bf2f((uint32_t)(z >> 48 ) & 0xffff), scale, bias));
        __builtin_nontemporal_store(r, (f32x4*)(dst + g2 * 64 + k * 4));
    }
}

extern "C" void kernel_launch(void* const* d_in, const int* in_sizes, int n_in,
                              void* d_out, int out_size, void* d_ws, size_t ws_size,
                              hipStream_t stream) {
    const float* xyz1  = (const float*)d_in[0];
    const float* xyz2  = (const float*)d_in[1];
    const float* p1    = (const float*)d_in[2];
    const float* p2    = (const float*)d_in[3];
    const float* W     = (const float*)d_in[4];
    const float* gamma = (const float*)d_in[5];
    const float* beta  = (const float*)d_in[6];
    float* out = (float*)d_out;
    char* ws = (char*)d_ws;
    if (ws_size < (size_t)WS_NEED) return;

    int*      idxw     = (int*)(ws + IDXW_OFF);
    uint16_t* ztb      = (uint16_t*)(ws + ZTB_OFF);
    uint16_t* y1       = (uint16_t*)(ws + Y1_OFF);
    uint16_t* y2       = (uint16_t*)(ws + Y2_OFF);
    float*    partials = (float*)(ws + PART_OFF);

    hipLaunchKernelGGL(kA,  dim3(4608), dim3(256),  0, stream,
                       xyz1, xyz2, idxw, W, p1, p2, ztb, y1);
    hipLaunchKernelGGL(k3a, dim3(512),  dim3(1024), 0, stream,
                       y1, ztb, idxw, y2, partials);
    hipLaunchKernelGGL(k3c, dim3(4096), dim3(256),  0, stream,
                       y2, partials, gamma, beta, out);
}

// Round 14
// 89.009 us; speedup vs baseline: 2.4603x; 1.0902x over previous
//
#include <hip/hip_runtime.h>
#include <stdint.h>

// PointNet Feature Propagation, MI355X.  4 launches:
//  K0 : W f32 -> w1b bf16 [256][64], w2b bf16 [256][256]   (tiny)
//  A  : fused  k2_z = W2@p2 (0..511) + k1 three_nn (512..2559) + k2b y1=W1@p1 (2560..4607)
//  K3a: y2 = y1 + sum_k w_k * ztb[idx_k]  (LDS-staged gather) + BN partials
//  K3c: y2 -> LDS transpose -> (stats from partials) BN+ReLU -> d_out f32

#define B_   16
#define N_   4096
#define S_   1024
#define D1_  64
#define D2_  256
#define OC_  256

typedef __attribute__((ext_vector_type(8))) short bf16x8;
typedef __attribute__((ext_vector_type(4))) float f32x4;
typedef __attribute__((ext_vector_type(4))) unsigned int u32x4;
typedef __attribute__((ext_vector_type(2))) unsigned int u32x2;

// workspace layout (bytes)
#define IDXW_OFF 0u           // 2 MB
#define ZTB_OFF  2097152u     // 8 MB
#define Y1_OFF   10485760u    // 32 MB
#define Y2_OFF   44040192u    // 32 MB
#define PART_OFF 77594624u    // 64 KB
#define W1B_OFF  77662208u    // 32 KB
#define W2B_OFF  77694976u    // 128 KB
#define WS_NEED  77826048u

__device__ __forceinline__ uint16_t f2bf(float f) {
    union { float f; uint32_t u; } v; v.f = f;
    uint32_t r = v.u + 0x7FFFu + ((v.u >> 16) & 1u);   // RNE
    return (uint16_t)(r >> 16);
}
__device__ __forceinline__ float bf2f(uint32_t h) {
    union { uint32_t u; float f; } v; v.u = h << 16;
    return v.f;
}

#define INSERT(d, sidx, d0, d1, d2, i0, i1, i2) do {                      \
    bool ca = (d) < (d2); bool cb = (d) < (d1); bool cc = (d) < (d0);     \
    float _n1 = __builtin_amdgcn_fmed3f((d), (d0), (d1));                 \
    float _n2 = __builtin_amdgcn_fmed3f((d), (d1), (d2));                 \
    int _j2 = cb ? (i1) : (ca ? (sidx) : (i2));                           \
    int _j1 = cc ? (i0) : (cb ? (sidx) : (i1));                           \
    i0 = cc ? (sidx) : (i0);                                              \
    d0 = fminf((d), (d0)); d1 = _n1; d2 = _n2; i1 = _j1; i2 = _j2;        \
} while (0)

// ---------------- K0: weight conversion ----------------
__global__ void k0_prep(const float* __restrict__ W,
                        uint16_t* __restrict__ w1b, uint16_t* __restrict__ w2b) {
    int e = blockIdx.x * 256 + threadIdx.x;
    if (e >= OC_ * 320) return;
    int o = e / 320, c = e % 320;
    uint16_t b = f2bf(W[e]);
    if (c < 64) w1b[o * 64 + c] = b;
    else        w2b[o * 256 + (c - 64)] = b;
}

// ---------------- A: k2_z (0..511) + k1 (512..2559) + k2b (2560..4607) ----------------
__global__ void __launch_bounds__(256, 8)
kA(const float* __restrict__ xyz1, const float* __restrict__ xyz2,
   int* __restrict__ idxw, const float* __restrict__ p1,
   const float* __restrict__ p2, const uint16_t* __restrict__ w1b,
   const uint16_t* __restrict__ w2b, uint16_t* __restrict__ ztb,
   uint16_t* __restrict__ y1) {
    __shared__ char smem[16512];
    int i = blockIdx.x;
    int t = threadIdx.x, l = t & 63, w = t >> 6;
    if (i < 512) {
        // ---- k2_z: ztb = W2@p2; A staged in LDS (full K), W2 bf16 from L2 ----
        uint16_t* a_t = (uint16_t*)smem;   // [32 s][256 c] bf16, 512B rows, swz <<4
        int b = i >> 5, s0 = (i & 31) * 32;
        int sA = t & 31, cpg = t >> 5;
        const float* p2b = p2 + (size_t)b * D2_ * S_ + s0;
        #pragma unroll
        for (int j = 0; j < 16; j++) {
            int cp = cpg + 8 * j;
            float lo = p2b[(size_t)(2 * cp) * S_ + sA];
            float hi = p2b[(size_t)(2 * cp + 1) * S_ + sA];
            uint32_t pk = (uint32_t)f2bf(lo) | ((uint32_t)f2bf(hi) << 16);
            *(uint32_t*)((char*)a_t + sA * 512 + ((cp * 4) ^ ((sA & 7) << 4))) = pk;
        }
        __syncthreads();
        f32x4 acc[2][4] = {};   // [mi(s16)][oj(o16)]
        int ls = l & 15, swzs = (ls & 7) << 4;
        #pragma unroll
        for (int ks = 0; ks < 8; ks++) {
            int co = ks * 32 + (l >> 4) * 8;
            bf16x8 a0 = *(const bf16x8*)((const char*)a_t + ls * 512 + ((co * 2) ^ swzs));
            bf16x8 a1 = *(const bf16x8*)((const char*)a_t + (16 + ls) * 512 + ((co * 2) ^ swzs));
            bf16x8 bbf[4];
            #pragma unroll
            for (int oj = 0; oj < 4; oj++) {
                int o = w * 64 + oj * 16 + ls;
                bbf[oj] = *(const bf16x8*)(w2b + (size_t)o * 256 + co);
            }
            #pragma unroll
            for (int oj = 0; oj < 4; oj++) {
                acc[0][oj] = __builtin_amdgcn_mfma_f32_16x16x32_bf16(a0, bbf[oj], acc[0][oj], 0, 0, 0);
                acc[1][oj] = __builtin_amdgcn_mfma_f32_16x16x32_bf16(a1, bbf[oj], acc[1][oj], 0, 0, 0);
            }
        }
        // direct fragment-native store: 16 lanes cover one 32B [s][16o] row
        #pragma unroll
        for (int mi = 0; mi < 2; mi++)
            #pragma unroll
            for (int oj = 0; oj < 4; oj++) {
                int og = w * 4 + oj;
                uint16_t* zb = ztb + ((size_t)(b * 16 + og) * S_ + s0 + mi * 16 + (l >> 4) * 4) * 16 + ls;
                #pragma unroll
                for (int r = 0; r < 4; r++)
                    zb[(size_t)r * 16] = f2bf(acc[mi][oj][r]);
            }
    } else if (i < 2560) {
        // ---- k1: three_nn (|s|^2 in pts.w; 3-fma distance; shift-invariant order) ----
        int j1 = i - 512;
        int b  = j1 >> 7;
        int n0 = (j1 & 127) * 32;
        float4* pts = (float4*)smem;    // [8 chunks][129]

        for (int s = t; s < S_; s += 256) {
            const float* p = xyz2 + ((size_t)b * S_ + s) * 3;
            float sx = p[0], sy = p[1], sz = p[2];
            float s2 = fmaf(sz, sz, fmaf(sy, sy, sx * sx));
            pts[(s >> 7) * 129 + (s & 127)] = make_float4(sx, sy, sz, s2);
        }
        __syncthreads();

        int chunk = t & 7, nidx = t >> 3;
        int n = n0 + nidx;
        const float* q = xyz1 + ((size_t)b * N_ + n) * 3;
        float ax = q[0], ay = q[1], az = q[2];
        float m2x = -2.0f * ax, m2y = -2.0f * ay, m2z = -2.0f * az;
        float q2 = fmaf(az, az, fmaf(ay, ay, ax * ax));

        float d0 = 3.4e38f, d1 = 3.4e38f, d2 = 3.4e38f;
        int   i0 = 0, i1 = 0, i2 = 0;

        const float4* base = pts + chunk * 129;
        int sbase = chunk * 128;
        #pragma unroll 4
        for (int j = 0; j < 128; j++) {
            float4 qq = base[j];
            int s = sbase + j;
            float d = fmaf(qq.x, m2x, fmaf(qq.y, m2y, fmaf(qq.z, m2z, qq.w)));
            INSERT(d, s, d0, d1, d2, i0, i1, i2);
        }
        #pragma unroll
        for (int m = 1; m <= 4; m <<= 1) {
            float e0 = __shfl_xor(d0, m), e1 = __shfl_xor(d1, m), e2 = __shfl_xor(d2, m);
            int   g0 = __shfl_xor(i0, m), g1 = __shfl_xor(i1, m), g2 = __shfl_xor(i2, m);
            INSERT(e0, g0, d0, d1, d2, i0, i1, i2);
            INSERT(e1, g1, d0, d1, d2, i0, i1, i2);
            INSERT(e2, g2, d0, d1, d2, i0, i1, i2);
        }
        if (chunk == 0) {
            float dd0 = d0 + q2, dd1 = d1 + q2, dd2 = d2 + q2;
            float r0 = 1.0f / (dd0 + 1e-8f), r1 = 1.0f / (dd1 + 1e-8f), r2 = 1.0f / (dd2 + 1e-8f);
            float rs = r0 + r1 + r2;
            float* fw = (float*)idxw;
            int bb = (b * N_ + n) * 8;
            idxw[bb + 0] = i0; idxw[bb + 1] = i1; idxw[bb + 2] = i2;
            fw[bb + 4] = r0 / rs; fw[bb + 5] = r1 / rs; fw[bb + 6] = r2 / rs;
        }
    } else {
        // ---- k2b: y1 = W1@p1, o-blocked bf16 ----
        int j2 = i - 2560;
        int b = j2 >> 7, n0 = (j2 & 127) * 32;
        int oW = w * 64;
        uint16_t* pt = (uint16_t*)smem;   // [32 n][64 c], 128B rows, swz <<4
        {
            int nn = t & 31;
            const float* p1b = p1 + (size_t)b * D1_ * N_ + n0;
            #pragma unroll
            for (int j = 0; j < 4; j++) {
                int cp = (t >> 5) + 8 * j;
                float lo = p1b[(size_t)(2 * cp) * N_ + nn];
                float hi = p1b[(size_t)(2 * cp + 1) * N_ + nn];
                uint32_t pk = (uint32_t)f2bf(lo) | ((uint32_t)f2bf(hi) << 16);
                *(uint32_t*)((char*)pt + nn * 128 + ((cp * 4) ^ ((nn & 7) << 4))) = pk;
            }
        }
        bf16x8 af[2][4];
        #pragma unroll
        for (int ks = 0; ks < 2; ks++)
            #pragma unroll
            for (int mi = 0; mi < 4; mi++) {
                int o = oW + mi * 16 + (l & 15);
                af[ks][mi] = *(const bf16x8*)(w1b + (size_t)o * 64 + ks * 32 + (l >> 4) * 8);
            }
        f32x4 acc[4][2] = {};   // [mi(o)][bj(n)]
        __syncthreads();
        #pragma unroll
        for (int ks = 0; ks < 2; ks++) {
            bf16x8 bf[2];
            int co = ks * 32 + (l >> 4) * 8;
            #pragma unroll
            for (int bj = 0; bj < 2; bj++) {
                int nn = bj * 16 + (l & 15);
                bf[bj] = *(const bf16x8*)((const char*)pt + nn * 128 + ((co * 2) ^ ((nn & 7) << 4)));
            }
            #pragma unroll
            for (int mi = 0; mi < 4; mi++)
                #pragma unroll
                for (int bj = 0; bj < 2; bj++)
                    acc[mi][bj] = __builtin_amdgcn_mfma_f32_16x16x32_bf16(
                        af[ks][mi], bf[bj], acc[mi][bj], 0, 0, 0);
        }
        #pragma unroll
        for (int mi = 0; mi < 4; mi++) {
            int og = w * 4 + mi;
            uint16_t* yb = y1 + ((size_t)(b * 16 + og)) * N_ * 16;
            #pragma unroll
            for (int bj = 0; bj < 2; bj++) {
                int n = n0 + bj * 16 + (l & 15);
                int oo = (l >> 4) * 4;
                u32x2 v;
                v.x = (uint32_t)f2bf(acc[mi][bj][0]) | ((uint32_t)f2bf(acc[mi][bj][1]) << 16);
                v.y = (uint32_t)f2bf(acc[mi][bj][2]) | ((uint32_t)f2bf(acc[mi][bj][3]) << 16);
                __builtin_nontemporal_store(v, (u32x2*)(yb + (size_t)n * 16 + oo));
            }
        }
    }
}

// ---------------- K3a: LDS-staged gather -> y2 bf16 + BN partials ----------------
__global__ void __launch_bounds__(1024, 8)
k3a(const uint16_t* __restrict__ y1, const uint16_t* __restrict__ ztb,
    const int* __restrict__ idxw, uint16_t* __restrict__ y2,
    float* __restrict__ partials) {
    __shared__ char zsm[49152];          // [1024 s][48B] rows (32B used)
    __shared__ float red[16][16][2];
    int bi = blockIdx.x;                 // 512: b*32 + og*2 + nh
    int b = bi >> 5, og = (bi >> 1) & 15, nh = bi & 1;
    int u = threadIdx.x, l = u & 63, w = u >> 6;   // 16 waves
    {
        const u32x4* src = (const u32x4*)(ztb + ((size_t)(b * 16 + og)) * S_ * 16);
        #pragma unroll
        for (int k = 0; k < 2; k++) {
            int g = k * 1024 + u;
            u32x4 v = src[g];
            *(u32x4*)(zsm + (g >> 1) * 48 + (g & 1) * 16) = v;
        }
    }
    __syncthreads();
    int q = l >> 2, sub = l & 3;
    float s1l[4] = {0.f, 0.f, 0.f, 0.f}, s2l[4] = {0.f, 0.f, 0.f, 0.f};
    int nbase = nh * 2048 + w * 128;
    const uint16_t* y1b = y1 + ((size_t)(b * 16 + og)) * N_ * 16;
    uint16_t* y2b = y2 + ((size_t)(b * 16 + og)) * N_ * 16;
    #pragma unroll 2
    for (int it = 0; it < 8; it++) {
        int n = nbase + it * 16 + q;
        u32x2 y1v = __builtin_nontemporal_load((const u32x2*)(y1b + (size_t)n * 16 + sub * 4));
        const int* ib = idxw + ((size_t)(b * N_ + n)) * 8;
        int4   iv = *(const int4*)ib;
        float4 wv = *((const float4*)ib + 1);
        u32x2 z0 = *(const u32x2*)(zsm + iv.x * 48 + sub * 8);
        u32x2 z1 = *(const u32x2*)(zsm + iv.y * 48 + sub * 8);
        u32x2 z2 = *(const u32x2*)(zsm + iv.z * 48 + sub * 8);
        float a0 = bf2f(y1v.x & 0xffff) + wv.x * bf2f(z0.x & 0xffff) + wv.y * bf2f(z1.x & 0xffff) + wv.z * bf2f(z2.x & 0xffff);
        float a1 = bf2f(y1v.x >> 16)    + wv.x * bf2f(z0.x >> 16)    + wv.y * bf2f(z1.x >> 16)    + wv.z * bf2f(z2.x >> 16);
        float a2 = bf2f(y1v.y & 0xffff) + wv.x * bf2f(z0.y & 0xffff) + wv.y * bf2f(z1.y & 0xffff) + wv.z * bf2f(z2.y & 0xffff);
        float a3 = bf2f(y1v.y >> 16)    + wv.x * bf2f(z0.y >> 16)    + wv.y * bf2f(z1.y >> 16)    + wv.z * bf2f(z2.y >> 16);
        s1l[0] += a0; s2l[0] += a0 * a0;
        s1l[1] += a1; s2l[1] += a1 * a1;
        s1l[2] += a2; s2l[2] += a2 * a2;
        s1l[3] += a3; s2l[3] += a3 * a3;
        u32x2 vv;
        vv.x = (uint32_t)f2bf(a0) | ((uint32_t)f2bf(a1) << 16);
        vv.y = (uint32_t)f2bf(a2) | ((uint32_t)f2bf(a3) << 16);
        __builtin_nontemporal_store(vv, (u32x2*)(y2b + (size_t)n * 16 + sub * 4));
    }
    #pragma unroll
    for (int m = 4; m <= 32; m <<= 1)
        #pragma unroll
        for (int j = 0; j < 4; j++) {
            s1l[j] += __shfl_xor(s1l[j], m);
            s2l[j] += __shfl_xor(s2l[j], m);
        }
    if (l < 4) {
        #pragma unroll
        for (int j = 0; j < 4; j++) {
            red[w][sub * 4 + j][0] = s1l[j];
            red[w][sub * 4 + j][1] = s2l[j];
        }
    }
    __syncthreads();
    if (u < 32) {
        int oi = u >> 1, st = u & 1;
        float s = 0.f;
        #pragma unroll
        for (int ww = 0; ww < 16; ww++) s += red[ww][oi][st];
        partials[(size_t)bi * 32 + oi * 2 + st] = s;
    }
}

// ---------------- K3c: stats + y2 -> LDS transpose -> BN+ReLU -> out ----------------
__global__ void __launch_bounds__(256, 8)
k3c(const uint16_t* __restrict__ y2, const float* __restrict__ partials,
    const float* __restrict__ gamma, const float* __restrict__ beta,
    float* __restrict__ out) {
    __shared__ uint16_t ty[16 * 256];   // [16 o][256 n] bf16, byte XOR bit4 by (o&7)
    __shared__ float stat[32];
    __shared__ float sbsh[32];
    int bi = blockIdx.x;                // 4096: b*256 + og*16 + nc
    int b = bi >> 8, og = (bi >> 4) & 15, nc = bi & 15;
    int u = threadIdx.x;
    const uint16_t* src = y2 + (((size_t)(b * 16 + og)) * N_ + nc * 256) * 16;
    u32x4 va = __builtin_nontemporal_load((const u32x4*)(src + (size_t)u * 16));
    u32x4 vb = __builtin_nontemporal_load((const u32x4*)(src + (size_t)u * 16 + 8));
    if (u < 32) {
        int oi = u >> 1, st = u & 1;
        float s = 0.f;
        #pragma unroll 4
        for (int t2 = 0; t2 < 32; t2++) {
            int row = (t2 >> 1) * 32 + og * 2 + (t2 & 1);
            s += partials[(size_t)row * 32 + oi * 2 + st];
        }
        stat[u] = s;
    }
    __syncthreads();
    if (u < 16) {
        float mean = stat[u * 2] / 65536.0f;
        float var  = stat[u * 2 + 1] / 65536.0f - mean * mean;
        int o_g = og * 16 + u;
        float scale = gamma[o_g] * rsqrtf(var + 1e-5f);
        sbsh[u * 2]     = scale;
        sbsh[u * 2 + 1] = beta[o_g] - mean * scale;
    }
    uint32_t words[8] = {va.x, va.y, va.z, va.w, vb.x, vb.y, vb.z, vb.w};
    #pragma unroll
    for (int h = 0; h < 8; h++) {
        int o0 = h * 2, o1 = h * 2 + 1;
        *(uint16_t*)((char*)ty + o0 * 512 + ((u * 2) ^ ((o0 & 7) << 4))) = (uint16_t)(words[h] & 0xffff);
        *(uint16_t*)((char*)ty + o1 * 512 + ((u * 2) ^ ((o1 & 7) << 4))) = (uint16_t)(words[h] >> 16);
    }
    __syncthreads();
    int o = u >> 4, k = u & 15;
    int x = (o & 7) << 4;
    int o_g = og * 16 + o;
    float scale = sbsh[o * 2], bias = sbsh[o * 2 + 1];
    float* dst = out + ((size_t)(b * OC_ + o_g)) * N_ + nc * 256;
    #pragma unroll
    for (int g2 = 0; g2 < 4; g2++) {
        uint64_t z = *(const uint64_t*)((const char*)ty + o * 512 + ((g2 * 128 + k * 8) ^ x));
        f32x4 r;
        r.x = fmaxf(0.f, fmaf(bf2f((uint32_t)(z       ) & 0xffff), scale, bias));
        r.y = fmaxf(0.f, fmaf(bf2f((uint32_t)(z >> 16 ) & 0xffff), scale, bias));
        r.z = fmaxf(0.f, fmaf(bf2f((uint32_t)(z >> 32 ) & 0xffff), scale, bias));
        r.w = fmaxf(0.f, fmaf(bf2f((uint32_t)(z >> 48 ) & 0xffff), scale, bias));
        __builtin_nontemporal_store(r, (f32x4*)(dst + g2 * 64 + k * 4));
    }
}

extern "C" void kernel_launch(void* const* d_in, const int* in_sizes, int n_in,
                              void* d_out, int out_size, void* d_ws, size_t ws_size,
                              hipStream_t stream) {
    const float* xyz1  = (const float*)d_in[0];
    const float* xyz2  = (const float*)d_in[1];
    const float* p1    = (const float*)d_in[2];
    const float* p2    = (const float*)d_in[3];
    const float* W     = (const float*)d_in[4];
    const float* gamma = (const float*)d_in[5];
    const float* beta  = (const float*)d_in[6];
    float* out = (float*)d_out;
    char* ws = (char*)d_ws;
    if (ws_size < (size_t)WS_NEED) return;

    int*      idxw     = (int*)(ws + IDXW_OFF);
    uint16_t* ztb      = (uint16_t*)(ws + ZTB_OFF);
    uint16_t* y1       = (uint16_t*)(ws + Y1_OFF);
    uint16_t* y2       = (uint16_t*)(ws + Y2_OFF);
    float*    partials = (float*)(ws + PART_OFF);
    uint16_t* w1b      = (uint16_t*)(ws + W1B_OFF);
    uint16_t* w2b      = (uint16_t*)(ws + W2B_OFF);

    hipLaunchKernelGGL(k0_prep, dim3(320),  dim3(256),  0, stream, W, w1b, w2b);
    hipLaunchKernelGGL(kA,      dim3(4608), dim3(256),  0, stream,
                       xyz1, xyz2, idxw, p1, p2, w1b, w2b, ztb, y1);
    hipLaunchKernelGGL(k3a,     dim3(512),  dim3(1024), 0, stream,
                       y1, ztb, idxw, y2, partials);
    hipLaunchKernelGGL(k3c,     dim3(4096), dim3(256),  0, stream,
                       y2, partials, gamma, beta, out);
}